// Round 6
// baseline (262.211 us; speedup 1.0000x reference)
//
#include <hip/hip_runtime.h>

#define NAG 12
#define NTH 4096
#define NEDGE 132
#define ENVW 2     // envs per WORKGROUP (shared by both waves)
#define WPB 2      // waves per workgroup (R15: split env-pair's serial chain across 2 waves)
#define LDB 72     // bf16 node-buffer row stride: 144 B, 16B-aligned, 2-way banks (free)
#define LDT 20     // mst col stride (bf16): 40 B -> 8B-aligned b64, low-conflict (R13 profile)

typedef __bf16 bf16_8 __attribute__((ext_vector_type(8)));
typedef __bf16 bf16_4 __attribute__((ext_vector_type(4)));
typedef float  f32x4  __attribute__((ext_vector_type(4)));

#define MFMA(a,b,c) __builtin_amdgcn_mfma_f32_16x16x32_bf16((a),(b),(c),0,0,0)

// ws layout:
//   frag region: 109 frags x 1024 B (64 lanes x 16 B)          [0, 111616)
//     0..3         : W_embed, nt
//     L = 4 + l*48 : We1a: L+nt*2+kh | We1b: L+8+nt*2+kh | We2: L+16+nt*2+kh
//                    Wh1: L+24+nt*4+ks | Wh2: L+40+nt*2+kh
//     100..108     : S segment-indicator A-frags, one per 16-edge tile t
//                    (k=0..15 live, k=16..31 zero)
//   bias region (fp32): float idx 27904 + ((l*4+w)*64+lane)*4  [111616, 119808)
//   bx region  (fp32): float idx 29952 + l*64 + lane           [119808, 120320)
#define WS_FRAGS 109
#define WS_BIAS_F32 27904
#define WS_BX_F32   29952
#define WS_BYTES 120320

__device__ __forceinline__ float silu_f(float z) {
    float e = __expf(-z);
    return z * __builtin_amdgcn_rcpf(1.0f + e);
}

// B-frag from fp32 row-major [K][64]: lane holds B[kbase+q*8+j][n]  (verified R2)
__device__ __forceinline__ bf16_8 loadB64(const float* __restrict__ W, int kbase, int n, int q) {
    bf16_8 b;
    #pragma unroll
    for (int j = 0; j < 8; ++j) b[j] = (__bf16)W[(kbase + q*8 + j) * 64 + n];
    return b;
}

// A-frag from 8 consecutive fp32 (16B-aligned)
__device__ __forceinline__ bf16_8 packA8(const float* S) {
    f32x4 u = *(const f32x4*)S, v = *(const f32x4*)(S + 4);
    bf16_8 a;
    a[0]=(__bf16)u.x; a[1]=(__bf16)u.y; a[2]=(__bf16)u.z; a[3]=(__bf16)u.w;
    a[4]=(__bf16)v.x; a[5]=(__bf16)v.y; a[6]=(__bf16)v.z; a[7]=(__bf16)v.w;
    return a;
}

// pack bf16_8 from two f32x4
__device__ __forceinline__ bf16_8 packA8v(f32x4 u, f32x4 v) {
    bf16_8 a;
    a[0]=(__bf16)u.x; a[1]=(__bf16)u.y; a[2]=(__bf16)u.z; a[3]=(__bf16)u.w;
    a[4]=(__bf16)v.x; a[5]=(__bf16)v.y; a[6]=(__bf16)v.z; a[7]=(__bf16)v.w;
    return a;
}

// ---- prep: pack weight B-fragments (bf16) + S-frags + biases into d_ws ----
__global__ __launch_bounds__(64) void prep_frags(
    const float* __restrict__ W_embed, const float* __restrict__ We1,
    const float* __restrict__ We2, const float* __restrict__ Wh1,
    const float* __restrict__ Wh2,
    const float* __restrict__ be1, const float* __restrict__ be2,
    const float* __restrict__ bh1, const float* __restrict__ bh2,
    const float* __restrict__ bx, __bf16* __restrict__ wsb)
{
    const int f = blockIdx.x, lane = threadIdx.x;
    const int q = lane >> 4, n16 = lane & 15;
    float* wsf = (float*)wsb;
    if (f < 100) {
        const float* src; int kbase, nbase;
        if (f < 4) { src = W_embed; kbase = 0; nbase = f * 16; }
        else {
            int g0 = f - 4, l = g0 / 48, r = g0 % 48;
            if      (r < 8)  { int nt=r>>1, kh=r&1;            src = We1 + l*NEDGE*64; kbase = kh*32;      nbase = nt*16; }
            else if (r < 16) { int rr=r-8,  nt=rr>>1, kh=rr&1; src = We1 + l*NEDGE*64; kbase = 64 + kh*32; nbase = nt*16; }
            else if (r < 24) { int rr=r-16, nt=rr>>1, kh=rr&1; src = We2 + l*64*64;    kbase = kh*32;      nbase = nt*16; }
            else if (r < 40) { int rr=r-24, nt=rr>>2, ks=rr&3; src = Wh1 + l*128*64;   kbase = ks*32;      nbase = nt*16; }
            else             { int rr=r-40, nt=rr>>1, kh=rr&1; src = Wh2 + l*64*64;    kbase = kh*32;      nbase = nt*16; }
        }
        bf16_8 b = loadB64(src, kbase, nbase + n16, q);
        *(bf16_8*)(wsb + (size_t)f * 512 + lane * 8) = b;
    } else if (f < WS_FRAGS) {
        // per-tile S-frag: A[row=node n16][k] = 1 iff edge t*16+k belongs to node n16
        // (k>=16 and out-of-range edges -> 0, killing the zeroed B-frag half + padding)
        int t = f - 100;
        bf16_8 b;
        #pragma unroll
        for (int j = 0; j < 8; ++j) {
            int k = q * 8 + j;
            int e = t * 16 + k;
            b[j] = (k < 16 && e < NEDGE && (e / 11) == n16) ? (__bf16)1.0f : (__bf16)0.0f;
        }
        *(bf16_8*)(wsb + (size_t)f * 512 + lane * 8) = b;
    } else if (f < WS_FRAGS + 8) {
        int f2 = f - WS_FRAGS, l = f2 >> 2, w = f2 & 3;
        const float* src = (w == 0 ? be1 : w == 1 ? be2 : w == 2 ? bh1 : bh2) + l * 64;
        f32x4 v = { src[n16], src[16 + n16], src[32 + n16], src[48 + n16] };
        *(f32x4*)(wsf + WS_BIAS_F32 + ((size_t)(l*4 + w) * 64 + lane) * 4) = v;
    } else {
        #pragma unroll
        for (int l = 0; l < 2; ++l)
            wsf[WS_BX_F32 + l*64 + lane] = (n16 < 4) ? bx[l*4 + n16] : 0.f;
    }
}

template<bool WS>
__device__ __forceinline__ bf16_8 frg(const __bf16* __restrict__ wsb, int fid,
                                      const float* __restrict__ src, int kbase, int n, int lane) {
    if (WS) return *(const bf16_8*)(wsb + (size_t)fid * 512 + lane * 8);
    else    return loadB64(src, kbase, n, (lane >> 4));
}

// ---- main: 2-WAVE COOPERATIVE WG per env-pair (R15, resubmit after infra flake) ----
// R11-R14 falsified: LDS residency, grid packing, atomic wave alloc, I$ capacity
// (occupancy pinned 11.3-11.5%, dur 145-153 across all). Occupancy arithmetic:
// ~3.6 avg waves/CU => ~67us per wave => ~90% per-wave stall that co-resident
// waves never fill. Only per-wave-chain levers ever helped. ENVW=4 spills,
// ENVW=3 is geometrically poisoned (4096 % 3). New axis: HALVE the per-wave
// serial chain by splitting each env-pair's pipeline across 2 waves:
//   - embed/StageA/Wh1/Wh2 split by nt (wave w owns nt in {2w,2w+1})
//   - edge loop split by tiles (wave0: t0-3, wave1: t4-8)
//   - xacc split by rows; 4 __syncthreads per layer (all at uniform control flow)
// Agg = per-tile MFMA with K-top-zeroed S-frags (q<2 B-frag loads) -> single
// mst buffer at LDT=20 (restores R13's low-conflict profile), partials merged
// fp32 via sAg. NOTE (R3/R4/R8): no occupancy-hint attrs (spill storms);
// FETCH_SIZE is the spill tripwire.
template<bool WS>
__global__ void __launch_bounds__(64 * WPB) egnn15(
    const float* __restrict__ h0, const float* __restrict__ x0,
    const float* __restrict__ W_embed, const float* __restrict__ b_embed,
    const float* __restrict__ We1, const float* __restrict__ be1,
    const float* __restrict__ We2, const float* __restrict__ be2,
    const float* __restrict__ Wx, const float* __restrict__ bx,
    const float* __restrict__ Wh1, const float* __restrict__ bh1,
    const float* __restrict__ Wh2, const float* __restrict__ bh2,
    const float* __restrict__ w_act, const float* __restrict__ log_std,
    const __bf16* __restrict__ wsb, float* __restrict__ out)
{
    // 37568 B -> 4 WGs/CU capacity (residency never gated anyway)
    __shared__ __align__(16) __bf16 sh  [ENVW][NAG * LDB];
    __shared__ __align__(16) __bf16 sHa [ENVW][NAG * LDB];
    __shared__ __align__(16) __bf16 sHb [ENVW][NAG * LDB];
    __shared__ __align__(16) __bf16 mst [WPB][ENVW][64 * LDT];
    __shared__ __align__(16) float  sAg [WPB][ENVW][NAG * 64];   // fp32 agg partials
    __shared__ __align__(16) float  sx  [ENVW][NAG * 16];
    __shared__ __align__(16) __bf16 sWcB[ENVW][NEDGE * 4];
    __shared__ __align__(16) float  sWb [4 * 64];

    const int tid  = threadIdx.x;
    const int wv   = tid >> 6;
    const int lane = tid & 63;
    const int q = lane >> 4, n16 = lane & 15;
    const int rowA = (n16 < NAG) ? n16 : (NAG - 1);
    const int env0 = blockIdx.x * ENVW;
    const float* wsf = (const float*)wsb;

    // ---- constant log-prob half of the output ----
    if (tid < NAG * 3) {
        int d = tid % 3;
        float lp = -log_std[d] - 0.9189385332046727f;
        #pragma unroll
        for (int ep = 0; ep < ENVW; ++ep)
            out[NTH * NAG * 3 + (env0 + ep) * (NAG*3) + tid] = lp;
    }

    // ---- load x (both envs: 288 floats, 128-thread stride) ----
    #pragma unroll
    for (int p = 0; p < 3; ++p) {
        int idx = p * 128 + tid;
        if (idx < ENVW * 144) {
            int ep = idx / 144, r2 = idx - ep * 144;
            sx[ep][(r2 / 12) * 16 + r2 % 12] = x0[(env0) * NAG * 12 + idx];
        }
    }

    // ---- embed: h = h0 @ W_embed + b (nt split across waves) ----
    f32x4 hC[ENVW][2];
    {
        bf16_8 a[ENVW];
        #pragma unroll
        for (int ep = 0; ep < ENVW; ++ep)
            a[ep] = packA8(h0 + ((env0 + ep) * NAG + rowA) * 32 + q * 8);
        #pragma unroll
        for (int nt2 = 0; nt2 < 2; ++nt2) {
            int nt = wv * 2 + nt2;
            bf16_8 b = frg<WS>(wsb, nt, W_embed, 0, nt*16 + n16, lane);
            float bias = b_embed[nt*16 + n16];
            #pragma unroll
            for (int ep = 0; ep < ENVW; ++ep) {
                f32x4 acc = {0.f,0.f,0.f,0.f};
                acc = MFMA(a[ep], b, acc);
                #pragma unroll
                for (int r = 0; r < 4; ++r) acc[r] += bias;
                hC[ep][nt2] = acc;
            }
        }
        #pragma unroll
        for (int ep = 0; ep < ENVW; ++ep)
            #pragma unroll
            for (int nt2 = 0; nt2 < 2; ++nt2)
                #pragma unroll
                for (int r = 0; r < 4; ++r) {
                    int row = q*4 + r;
                    if (row < NAG) sh[ep][row*LDB + (wv*2+nt2)*16 + n16] = (__bf16)hC[ep][nt2][r];
                }
    }
    __syncthreads();   // B0: full sh (both waves' cols) before Stage A row reads

    #pragma unroll 1
    for (int l = 0; l < 2; ++l) {
        const float* We1l = We1 + l * NEDGE * 64;
        const float* be1l = be1 + l * 64;
        const float* be2l = be2 + l * 64;
        const float* Wxl  = Wx  + l * 64 * 4;
        const float* bxl  = bx  + l * 4;
        const float* We2l = We2 + l * 64 * 64;
        const float* Wh1l = Wh1 + l * 128 * 64;
        const float* bh1l = bh1 + l * 64;
        const float* Wh2l = Wh2 + l * 64 * 64;
        const float* bh2l = bh2 + l * 64;
        const int L = 4 + l * 48;

        f32x4 be2q;
        float be1s[2], bh1s[2], bh2s[2], bxv;
        if (WS) {
            const float* bb = wsf + WS_BIAS_F32 + (size_t)(l*4) * 256 + lane * 4;
            be2q = *(const f32x4*)(bb + 256);
            #pragma unroll
            for (int nt2 = 0; nt2 < 2; ++nt2) {
                int nt = wv*2 + nt2;
                be1s[nt2] = bb[nt];
                bh1s[nt2] = bb[512 + nt];
                bh2s[nt2] = bb[768 + nt];
            }
            bxv = wsf[WS_BX_F32 + l*64 + lane];
        } else {
            #pragma unroll
            for (int nt = 0; nt < 4; ++nt) be2q[nt] = be2l[nt*16+n16];
            #pragma unroll
            for (int nt2 = 0; nt2 < 2; ++nt2) {
                int nt = wv*2 + nt2;
                be1s[nt2] = be1l[nt*16+n16];
                bh1s[nt2] = bh1l[nt*16+n16];
                bh2s[nt2] = bh2l[nt*16+n16];
            }
            bxv = (n16 < 4) ? bxl[n16] : 0.f;
        }

        // ---- Stage A: Ha/Hb, nt split across waves ----
        {
            bf16_8 a0[ENVW], a1[ENVW];
            #pragma unroll
            for (int ep = 0; ep < ENVW; ++ep) {
                a0[ep] = *(const bf16_8*)(sh[ep] + rowA*LDB + q*8);
                a1[ep] = *(const bf16_8*)(sh[ep] + rowA*LDB + 32 + q*8);
            }
            #pragma unroll
            for (int nt2 = 0; nt2 < 2; ++nt2) {
                int nt = wv*2 + nt2;
                bf16_8 b0 = frg<WS>(wsb, L+nt*2+0,   We1l, 0,  nt*16+n16, lane);
                bf16_8 b1 = frg<WS>(wsb, L+nt*2+1,   We1l, 32, nt*16+n16, lane);
                bf16_8 c0 = frg<WS>(wsb, L+8+nt*2+0, We1l, 64, nt*16+n16, lane);
                bf16_8 c1 = frg<WS>(wsb, L+8+nt*2+1, We1l, 96, nt*16+n16, lane);
                #pragma unroll
                for (int ep = 0; ep < ENVW; ++ep) {
                    f32x4 aA = {0.f,0.f,0.f,0.f}, aB = {0.f,0.f,0.f,0.f};
                    aA = MFMA(a0[ep], b0, aA); aA = MFMA(a1[ep], b1, aA);
                    aB = MFMA(a0[ep], c0, aB); aB = MFMA(a1[ep], c1, aB);
                    #pragma unroll
                    for (int r = 0; r < 4; ++r) {
                        int row = q*4 + r;
                        if (row < NAG) {
                            sHa[ep][row*LDB + nt*16+n16] = (__bf16)(aA[r] + be1s[nt2]);
                            sHb[ep][row*LDB + nt*16+n16] = (__bf16)aB[r];
                        }
                    }
                }
            }
        }
        #pragma unroll
        for (int p2 = 0; p2 < 2; ++p2) {
            int p = wv*2 + p2;
            sWb[p*64 + lane] = We1l[(128+p)*64 + lane];
        }
        __syncthreads();   // B1: full sHa/sHb/sWb before edge gathers

        // ---- Edge stage: tile split (wave0: t0-3, wave1: t4-8) ----
        f32x4 aggC[ENVW][4];
        #pragma unroll
        for (int ep = 0; ep < ENVW; ++ep)
            #pragma unroll
            for (int nt = 0; nt < 4; ++nt) aggC[ep][nt] = (f32x4){0.f,0.f,0.f,0.f};
        bf16_8 w2f[4][2], wxf[2];
        #pragma unroll
        for (int nt = 0; nt < 4; ++nt) {
            w2f[nt][0] = frg<WS>(wsb, L+16+nt*2+0, We2l, 0,  nt*16+n16, lane);
            w2f[nt][1] = frg<WS>(wsb, L+16+nt*2+1, We2l, 32, nt*16+n16, lane);
        }
        #pragma unroll
        for (int kh = 0; kh < 2; ++kh) {
            bf16_8 b;
            #pragma unroll
            for (int j2 = 0; j2 < 8; ++j2)
                b[j2] = (n16 < 4) ? (__bf16)Wxl[(kh*32 + q*8 + j2)*4 + n16] : (__bf16)0.f;
            wxf[kh] = b;
        }

        #pragma unroll 1
        for (int t = (wv ? 4 : 0); t < (wv ? 9 : 4); ++t) {
            const int e  = t*16 + n16;
            const int ec = (e < NEDGE) ? e : (NEDGE - 1);
            const int i  = ec / 11;
            const int jj = ec - i * 11;
            const int j  = jj + (jj >= i);
            f32x4 rdv[ENVW];
            #pragma unroll
            for (int ep = 0; ep < ENVW; ++ep) {
                f32x4 rd = {0.f,0.f,0.f,0.f};
                #pragma unroll
                for (int d = 0; d < 3; ++d) {
                    f32x4 xi = *(const f32x4*)(sx[ep] + i*16 + d*4);
                    f32x4 xj = *(const f32x4*)(sx[ep] + j*16 + d*4);
                    f32x4 df = xi - xj;
                    rd += df * df;
                }
                rdv[ep] = rd;
            }
            bf16_8 af[ENVW][2];
            #pragma unroll
            for (int kh = 0; kh < 2; ++kh) {
                const int cb = kh*32 + q*8;
                f32x4 wa[4], wb[4];
                #pragma unroll
                for (int v = 0; v < 4; ++v) {
                    wa[v] = *(const f32x4*)(sWb + v*64 + cb);
                    wb[v] = *(const f32x4*)(sWb + v*64 + cb + 4);
                }
                #pragma unroll
                for (int ep = 0; ep < ENVW; ++ep) {
                    bf16_8 ha = *(const bf16_8*)(sHa[ep] + i*LDB + cb);
                    bf16_8 hb = *(const bf16_8*)(sHb[ep] + j*LDB + cb);
                    f32x4 wr0 = {0.f,0.f,0.f,0.f}, wr1 = {0.f,0.f,0.f,0.f};
                    #pragma unroll
                    for (int v = 0; v < 4; ++v) {
                        wr0 += rdv[ep][v] * wa[v]; wr1 += rdv[ep][v] * wb[v];
                    }
                    bf16_8 a;
                    #pragma unroll
                    for (int c = 0; c < 4; ++c)
                        a[c]   = (__bf16)silu_f((float)ha[c]   + (float)hb[c]   + wr0[c]);
                    #pragma unroll
                    for (int c = 0; c < 4; ++c)
                        a[4+c] = (__bf16)silu_f((float)ha[4+c] + (float)hb[4+c] + wr1[c]);
                    af[ep][kh] = a;
                }
            }
            // m = silu(s1@We2 + be2) -> per-env col-major staging (own wave's buffer)
            #pragma unroll
            for (int ep = 0; ep < ENVW; ++ep) {
                __bf16* mT = &mst[wv][ep][0];
                #pragma unroll
                for (int nt = 0; nt < 4; ++nt) {
                    f32x4 acc = {0.f,0.f,0.f,0.f};
                    acc = MFMA(af[ep][0], w2f[nt][0], acc);
                    acc = MFMA(af[ep][1], w2f[nt][1], acc);
                    bf16_4 mv;
                    #pragma unroll
                    for (int r = 0; r < 4; ++r) mv[r] = (__bf16)silu_f(acc[r] + be2q[nt]);
                    *(bf16_4*)(mT + (nt*16 + n16)*LDT + q*4) = mv;
                }
            }
            // wc = m@Wx + bx via MFMA (per env)
            #pragma unroll
            for (int ep = 0; ep < ENVW; ++ep) {
                const __bf16* mT = &mst[wv][ep][0];
                bf16_8 aw0, aw1;
                #pragma unroll
                for (int j2 = 0; j2 < 8; ++j2) {
                    aw0[j2] = mT[(q*8 + j2)*LDT + n16];
                    aw1[j2] = mT[(32 + q*8 + j2)*LDT + n16];
                }
                f32x4 acc = {0.f,0.f,0.f,0.f};
                acc = MFMA(aw0, wxf[0], acc);
                acc = MFMA(aw1, wxf[1], acc);
                if (n16 < 4) {
                    #pragma unroll
                    for (int r = 0; r < 4; ++r) {
                        int row = t*16 + q*4 + r;
                        if (row < NEDGE) sWcB[ep][row*4 + n16] = (__bf16)(acc[r] + bxv);
                    }
                }
            }
            // agg += S_t @ m   (K=16 live; q>=2 B-frag half is zero x zero-S)
            bf16_8 sfr;
            if (WS) {
                sfr = *(const bf16_8*)(wsb + (size_t)(100 + t) * 512 + lane * 8);
            } else {
                #pragma unroll
                for (int j2 = 0; j2 < 8; ++j2) {
                    int k = q*8 + j2, e2 = t*16 + k;
                    sfr[j2] = (k < 16 && e2 < NEDGE && (e2 / 11) == n16) ? (__bf16)1.0f : (__bf16)0.0f;
                }
            }
            #pragma unroll
            for (int ep = 0; ep < ENVW; ++ep) {
                const __bf16* mT = &mst[wv][ep][0];
                #pragma unroll
                for (int nt = 0; nt < 4; ++nt) {
                    bf16_8 mb;
                    #pragma unroll
                    for (int c = 0; c < 8; ++c) mb[c] = (__bf16)0.f;
                    if (q < 2) mb = *(const bf16_8*)(mT + (nt*16 + n16)*LDT + q*8);
                    aggC[ep][nt] = MFMA(sfr, mb, aggC[ep][nt]);
                }
            }
        }
        // partial agg (fp32) -> sAg[wv]
        #pragma unroll
        for (int ep = 0; ep < ENVW; ++ep)
            #pragma unroll
            for (int nt = 0; nt < 4; ++nt)
                #pragma unroll
                for (int r = 0; r < 4; ++r) {
                    int row = q*4 + r;
                    if (row < NAG) sAg[wv][ep][row*64 + nt*16+n16] = aggC[ep][nt][r];
                }
        __syncthreads();   // B2: full sWcB + both agg partials

        // ---- xacc (pre-update x reads, 128-thread split) ----
        float xn[ENVW][2];
        #pragma unroll
        for (int p = 0; p < 2; ++p) {
            int idx = p*128 + tid;
            int xi = idx / 12, dv = idx % 12, v = dv & 3;
            bool act = idx < 144;
            int xic = act ? xi : 0;
            #pragma unroll
            for (int ep = 0; ep < ENVW; ++ep) {
                float xiv = sx[ep][xic*16 + dv];
                float acc = 0.f;
                #pragma unroll
                for (int j2 = 0; j2 < NAG; ++j2) {
                    int e2 = xic*11 + j2 - (j2 > xic ? 1 : 0);
                    e2 = (e2 < NEDGE) ? e2 : (NEDGE - 1);
                    float term = (xiv - sx[ep][j2*16 + dv]) * (float)sWcB[ep][e2*4 + v];
                    acc += (j2 == xic) ? 0.f : term;
                }
                xn[ep][p] = act ? (xiv + acc * (1.0f / 11.0f)) : 0.f;
            }
        }
        // ---- Wh1: t1 = silu([h,agg]@Wh1 + bh1) -> sHa (nt split) ----
        {
            bf16_8 ah0[ENVW], ah1[ENVW], ag0[ENVW], ag1[ENVW];
            #pragma unroll
            for (int ep = 0; ep < ENVW; ++ep) {
                ah0[ep] = *(const bf16_8*)(sh[ep] + rowA*LDB + q*8);
                ah1[ep] = *(const bf16_8*)(sh[ep] + rowA*LDB + 32 + q*8);
                const float* g0 = sAg[0][ep] + rowA*64;
                const float* g1 = sAg[1][ep] + rowA*64;
                f32x4 u0 = *(const f32x4*)(g0 + q*8)      + *(const f32x4*)(g1 + q*8);
                f32x4 v0 = *(const f32x4*)(g0 + q*8 + 4)  + *(const f32x4*)(g1 + q*8 + 4);
                f32x4 u1 = *(const f32x4*)(g0 + 32 + q*8) + *(const f32x4*)(g1 + 32 + q*8);
                f32x4 v1 = *(const f32x4*)(g0 + 36 + q*8) + *(const f32x4*)(g1 + 36 + q*8);
                ag0[ep] = packA8v(u0, v0);
                ag1[ep] = packA8v(u1, v1);
            }
            #pragma unroll
            for (int nt2 = 0; nt2 < 2; ++nt2) {
                int nt = wv*2 + nt2;
                bf16_8 b0 = frg<WS>(wsb, L+24+nt*4+0, Wh1l, 0,  nt*16+n16, lane);
                bf16_8 b1 = frg<WS>(wsb, L+24+nt*4+1, Wh1l, 32, nt*16+n16, lane);
                bf16_8 b2 = frg<WS>(wsb, L+24+nt*4+2, Wh1l, 64, nt*16+n16, lane);
                bf16_8 b3 = frg<WS>(wsb, L+24+nt*4+3, Wh1l, 96, nt*16+n16, lane);
                #pragma unroll
                for (int ep = 0; ep < ENVW; ++ep) {
                    f32x4 acc = {0.f,0.f,0.f,0.f};
                    acc = MFMA(ah0[ep], b0, acc); acc = MFMA(ah1[ep], b1, acc);
                    acc = MFMA(ag0[ep], b2, acc); acc = MFMA(ag1[ep], b3, acc);
                    #pragma unroll
                    for (int r = 0; r < 4; ++r) {
                        int row = q*4 + r;
                        if (row < NAG) sHa[ep][row*LDB + nt*16+n16] = (__bf16)silu_f(acc[r] + bh1s[nt2]);
                    }
                }
            }
        }
        __syncthreads();   // B3: all xacc reads done + full sHa (t1) written

        // ---- x writeback; Wh2: h += t1@Wh2 + bh2 (nt split) ----
        #pragma unroll
        for (int p = 0; p < 2; ++p) {
            int idx = p*128 + tid;
            if (idx < 144) {
                #pragma unroll
                for (int ep = 0; ep < ENVW; ++ep)
                    sx[ep][(idx/12)*16 + idx%12] = xn[ep][p];
            }
        }
        {
            bf16_8 at0[ENVW], at1[ENVW];
            #pragma unroll
            for (int ep = 0; ep < ENVW; ++ep) {
                at0[ep] = *(const bf16_8*)(sHa[ep] + rowA*LDB + q*8);
                at1[ep] = *(const bf16_8*)(sHa[ep] + rowA*LDB + 32 + q*8);
            }
            #pragma unroll
            for (int nt2 = 0; nt2 < 2; ++nt2) {
                int nt = wv*2 + nt2;
                bf16_8 b0 = frg<WS>(wsb, L+40+nt*2+0, Wh2l, 0,  nt*16+n16, lane);
                bf16_8 b1 = frg<WS>(wsb, L+40+nt*2+1, Wh2l, 32, nt*16+n16, lane);
                #pragma unroll
                for (int ep = 0; ep < ENVW; ++ep) {
                    f32x4 acc = {0.f,0.f,0.f,0.f};
                    acc = MFMA(at0[ep], b0, acc);
                    acc = MFMA(at1[ep], b1, acc);
                    #pragma unroll
                    for (int r = 0; r < 4; ++r) hC[ep][nt2][r] += acc[r] + bh2s[nt2];
                }
            }
            #pragma unroll
            for (int ep = 0; ep < ENVW; ++ep)
                #pragma unroll
                for (int nt2 = 0; nt2 < 2; ++nt2)
                    #pragma unroll
                    for (int r = 0; r < 4; ++r) {
                        int row = q*4 + r;
                        if (row < NAG) sh[ep][row*LDB + (wv*2+nt2)*16+n16] = (__bf16)hC[ep][nt2][r];
                    }
        }
        __syncthreads();   // B4: full sh + updated sx before next layer / epilogue
    }

    // ---- epilogue: mu only ----
    if (tid < NAG * 3) {
        int i = tid / 3, d = tid - i * 3;
        #pragma unroll
        for (int ep = 0; ep < ENVW; ++ep) {
            float mu = 0.f;
            #pragma unroll
            for (int v = 0; v < 4; ++v) mu += sx[ep][i*16 + d*4 + v] * w_act[v];
            out[(env0 + ep) * (NAG*3) + tid] = mu;
        }
    }
}

extern "C" void kernel_launch(void* const* d_in, const int* in_sizes, int n_in,
                              void* d_out, int out_size, void* d_ws, size_t ws_size,
                              hipStream_t stream) {
    // inputs: h0,x0,W_embed,b_embed,We1,be1,We2,be2,Wx,bx,Wh1,bh1,Wh2,bh2,w_act,log_std,row,col
    const float* h0   = (const float*)d_in[0];
    const float* x0   = (const float*)d_in[1];
    const float* Wem  = (const float*)d_in[2];
    const float* bem  = (const float*)d_in[3];
    const float* We1  = (const float*)d_in[4];
    const float* be1  = (const float*)d_in[5];
    const float* We2  = (const float*)d_in[6];
    const float* be2  = (const float*)d_in[7];
    const float* Wx   = (const float*)d_in[8];
    const float* bx   = (const float*)d_in[9];
    const float* Wh1  = (const float*)d_in[10];
    const float* bh1  = (const float*)d_in[11];
    const float* Wh2  = (const float*)d_in[12];
    const float* bh2  = (const float*)d_in[13];
    const float* wact = (const float*)d_in[14];
    const float* lstd = (const float*)d_in[15];
    float* out = (float*)d_out;

    if (ws_size >= (size_t)WS_BYTES) {
        prep_frags<<<dim3(WS_FRAGS + 9), dim3(64), 0, stream>>>(
            Wem, We1, We2, Wh1, Wh2, be1, be2, bh1, bh2, bx, (__bf16*)d_ws);
        egnn15<true><<<dim3(NTH / ENVW), dim3(64 * WPB), 0, stream>>>(
            h0, x0, Wem, bem, We1, be1, We2, be2, Wx, bx,
            Wh1, bh1, Wh2, bh2, wact, lstd, (const __bf16*)d_ws, out);
    } else {
        egnn15<false><<<dim3(NTH / ENVW), dim3(64 * WPB), 0, stream>>>(
            h0, x0, Wem, bem, We1, be1, We2, be2, Wx, bx,
            Wh1, bh1, Wh2, bh2, wact, lstd, nullptr, out);
    }
}

// Round 7
// 233.231 us; speedup vs baseline: 1.1243x; 1.1243x over previous
//
#include <hip/hip_runtime.h>

#define NAG 12
#define NTH 4096
#define NEDGE 132
#define ENVW 2    // envs per wave (R12's 4 spilled: VGPR=256 + 54MB scratch traffic)
#define NWAVE 4   // waves per workgroup (R13 best: atomic co-residency + I$ co-locality)
#define LDB 72    // bf16 node-buffer row stride: 144 B, 16B-aligned, 2-way banks (free)
#define LDT 20    // mstT col stride (bf16): 40 B -> 8B-aligned b64, low-conflict

typedef __bf16 bf16_8 __attribute__((ext_vector_type(8)));
typedef __bf16 bf16_4 __attribute__((ext_vector_type(4)));
typedef float  f32x4  __attribute__((ext_vector_type(4)));

#define MFMA(a,b,c) __builtin_amdgcn_mfma_f32_16x16x32_bf16((a),(b),(c),0,0,0)

__device__ __forceinline__ float silu_f(float z) {
    float e = __expf(-z);
    return z * __builtin_amdgcn_rcpf(1.0f + e);
}

// B-frag from fp32 row-major [K][64]: lane holds B[kbase+q*8+j][n]  (verified R2)
__device__ __forceinline__ bf16_8 loadB64(const float* __restrict__ W, int kbase, int n, int q) {
    bf16_8 b;
    #pragma unroll
    for (int j = 0; j < 8; ++j) b[j] = (__bf16)W[(kbase + q*8 + j) * 64 + n];
    return b;
}

// A-frag from 8 consecutive fp32 (16B-aligned)
__device__ __forceinline__ bf16_8 packA8(const float* S) {
    f32x4 u = *(const f32x4*)S, v = *(const f32x4*)(S + 4);
    bf16_8 a;
    a[0]=(__bf16)u.x; a[1]=(__bf16)u.y; a[2]=(__bf16)u.z; a[3]=(__bf16)u.w;
    a[4]=(__bf16)v.x; a[5]=(__bf16)v.y; a[6]=(__bf16)v.z; a[7]=(__bf16)v.w;
    return a;
}

// ---- main: R13 structure (best measured: 145.4us), prep kernel removed ----
// R16: R11-R15 falsified LDS residency, grid packing, atomic wave alloc, I$
// capacity, and cooperative chain-splitting as the limiter. Counters across all:
// VALUBusy ~44%, MfmaUtil ~5%, HBM ~0.5%, occupancy pinned 11.3% -> the floor
// is externally governed (CP pacing or DVFS), not source-addressable. Lock in
// the best config (R13: 4 independent waves/WG x 2 envs/wave, zero barriers)
// and remove the prep_frags dispatch (re-run on every graph replay; weights are
// L2/L3-resident on replays, so direct global B-frag loads via loadB64 -- the
// exact indexing prep used to build the frags -- cost a few hundred
// overlappable L2 hits per wave).
// NOTE (R3/R4/R8): occupancy-hint attributes cause allocator overshoot ->
// spill storms. Plain __launch_bounds__. FETCH_SIZE is the spill tripwire.
__global__ void __launch_bounds__(64 * NWAVE) egnn16(
    const float* __restrict__ h0, const float* __restrict__ x0,
    const float* __restrict__ W_embed, const float* __restrict__ b_embed,
    const float* __restrict__ We1, const float* __restrict__ be1,
    const float* __restrict__ We2, const float* __restrict__ be2,
    const float* __restrict__ Wx, const float* __restrict__ bx,
    const float* __restrict__ Wh1, const float* __restrict__ bh1,
    const float* __restrict__ Wh2, const float* __restrict__ bh2,
    const float* __restrict__ w_act, const float* __restrict__ log_std,
    float* __restrict__ out)
{
    // 80640 B total (4 x 20160) -> 2 blocks/CU = 8 waves/CU
    __shared__ __align__(16) __bf16 sh  [NWAVE][ENVW][NAG * LDB];
    __shared__ __align__(16) __bf16 sHa [NWAVE][ENVW][NAG * LDB];
    __shared__ __align__(16) __bf16 sHb [NWAVE][ENVW][NAG * LDB];
    __shared__ __align__(16) __bf16 mstT[NWAVE][ENVW][64 * LDT];
    __shared__ __align__(16) float  sx  [NWAVE][ENVW][NAG * 16];
    __shared__ __align__(16) __bf16 sWcB[NWAVE][ENVW][NEDGE * 4];
    __shared__ __align__(16) float  sWb [NWAVE][4 * 64];   // per-wave copy (no barriers)

    const int tid  = threadIdx.x;
    const int wv   = tid >> 6;
    const int lane = tid & 63;
    const int q = lane >> 4, n16 = lane & 15;
    const int rowA = (n16 < NAG) ? n16 : (NAG - 1);
    const int env0 = (blockIdx.x * NWAVE + wv) * ENVW;

    // ---- constant log-prob half of the output ----
    if (lane < NAG * 3) {
        int d = lane % 3;
        float lp = -log_std[d] - 0.9189385332046727f;
        #pragma unroll
        for (int ep = 0; ep < ENVW; ++ep)
            out[NTH * NAG * 3 + (env0 + ep) * (NAG*3) + lane] = lp;
    }

    // ---- load x (this wave's envs: ENVW*144 floats contiguous) ----
    #pragma unroll
    for (int p = 0; p < (ENVW * 144 + 63) / 64; ++p) {
        int idx = p * 64 + lane;
        if (idx < ENVW * 144) {
            int ep = idx / 144, r2 = idx - ep * 144;
            sx[wv][ep][(r2 / 12) * 16 + r2 % 12] = x0[(env0) * NAG * 12 + idx];
        }
    }

    // ---- embed: h = h0 @ W_embed + b ----
    f32x4 hC[ENVW][4];
    {
        bf16_8 a[ENVW];
        #pragma unroll
        for (int ep = 0; ep < ENVW; ++ep)
            a[ep] = packA8(h0 + ((env0 + ep) * NAG + rowA) * 32 + q * 8);
        #pragma unroll
        for (int nt = 0; nt < 4; ++nt) {
            bf16_8 b = loadB64(W_embed, 0, nt*16 + n16, q);
            float bias = b_embed[nt*16 + n16];
            #pragma unroll
            for (int ep = 0; ep < ENVW; ++ep) {
                f32x4 acc = {0.f,0.f,0.f,0.f};
                acc = MFMA(a[ep], b, acc);
                #pragma unroll
                for (int r = 0; r < 4; ++r) acc[r] += bias;
                hC[ep][nt] = acc;
            }
        }
        #pragma unroll
        for (int ep = 0; ep < ENVW; ++ep)
            #pragma unroll
            for (int nt = 0; nt < 4; ++nt)
                #pragma unroll
                for (int r = 0; r < 4; ++r) {
                    int row = q*4 + r;
                    if (row < NAG) sh[wv][ep][row*LDB + nt*16 + n16] = (__bf16)hC[ep][nt][r];
                }
    }

    #pragma unroll 1
    for (int l = 0; l < 2; ++l) {
        const float* We1l = We1 + l * NEDGE * 64;
        const float* be1l = be1 + l * 64;
        const float* be2l = be2 + l * 64;
        const float* Wxl  = Wx  + l * 64 * 4;
        const float* bxl  = bx  + l * 4;
        const float* We2l = We2 + l * 64 * 64;
        const float* Wh1l = Wh1 + l * 128 * 64;
        const float* bh1l = bh1 + l * 64;
        const float* Wh2l = Wh2 + l * 64 * 64;
        const float* bh2l = bh2 + l * 64;

        f32x4 be1q, be2q, bh1q, bh2q;
        float bxv;
        #pragma unroll
        for (int nt = 0; nt < 4; ++nt) {
            be1q[nt] = be1l[nt*16+n16]; be2q[nt] = be2l[nt*16+n16];
            bh1q[nt] = bh1l[nt*16+n16]; bh2q[nt] = bh2l[nt*16+n16];
        }
        bxv = (n16 < 4) ? bxl[n16] : 0.f;

        // ---- Stage A: Ha/Hb ----
        {
            bf16_8 a0[ENVW], a1[ENVW];
            #pragma unroll
            for (int ep = 0; ep < ENVW; ++ep) {
                a0[ep] = *(const bf16_8*)(sh[wv][ep] + rowA*LDB + q*8);
                a1[ep] = *(const bf16_8*)(sh[wv][ep] + rowA*LDB + 32 + q*8);
            }
            #pragma unroll
            for (int nt = 0; nt < 4; ++nt) {
                bf16_8 b0 = loadB64(We1l, 0,  nt*16+n16, q);
                bf16_8 b1 = loadB64(We1l, 32, nt*16+n16, q);
                bf16_8 c0 = loadB64(We1l, 64, nt*16+n16, q);
                bf16_8 c1 = loadB64(We1l, 96, nt*16+n16, q);
                #pragma unroll
                for (int ep = 0; ep < ENVW; ++ep) {
                    f32x4 aA = {0.f,0.f,0.f,0.f}, aB = {0.f,0.f,0.f,0.f};
                    aA = MFMA(a0[ep], b0, aA); aA = MFMA(a1[ep], b1, aA);
                    aB = MFMA(a0[ep], c0, aB); aB = MFMA(a1[ep], c1, aB);
                    #pragma unroll
                    for (int r = 0; r < 4; ++r) {
                        int row = q*4 + r;
                        if (row < NAG) {
                            sHa[wv][ep][row*LDB + nt*16+n16] = (__bf16)(aA[r] + be1q[nt]);
                            sHb[wv][ep][row*LDB + nt*16+n16] = (__bf16)aB[r];
                        }
                    }
                }
            }
        }
        #pragma unroll
        for (int p = 0; p < 4; ++p) sWb[wv][p*64 + lane] = We1l[(128+p)*64 + lane];

        // ---- Edge stage: 9 M-tiles x ENVW envs interleaved ----
        float agg[ENVW][NAG];
        #pragma unroll
        for (int ep = 0; ep < ENVW; ++ep)
            #pragma unroll
            for (int i = 0; i < NAG; ++i) agg[ep][i] = 0.f;
        bf16_8 w2f[4][2], wxf[2];
        #pragma unroll
        for (int nt = 0; nt < 4; ++nt) {
            w2f[nt][0] = loadB64(We2l, 0,  nt*16+n16, q);
            w2f[nt][1] = loadB64(We2l, 32, nt*16+n16, q);
        }
        #pragma unroll
        for (int kh = 0; kh < 2; ++kh) {
            bf16_8 b;
            #pragma unroll
            for (int j2 = 0; j2 < 8; ++j2)
                b[j2] = (n16 < 4) ? (__bf16)Wxl[(kh*32 + q*8 + j2)*4 + n16] : (__bf16)0.f;
            wxf[kh] = b;
        }

        #pragma unroll
        for (int t = 0; t < 9; ++t) {
            // env-independent index math (amortized over both envs)
            const int e  = t*16 + n16;
            const int ec = (e < NEDGE) ? e : (NEDGE - 1);
            const int i  = ec / 11;
            const int jj = ec - i * 11;
            const int j  = jj + (jj >= i);
            // A-frags for both envs
            bf16_8 af[ENVW][2];
            #pragma unroll
            for (int ep = 0; ep < ENVW; ++ep) {
                // radial recomputed on the fly; same d-order -> identical fp
                f32x4 rd = {0.f,0.f,0.f,0.f};
                #pragma unroll
                for (int d = 0; d < 3; ++d) {
                    f32x4 xi = *(const f32x4*)(sx[wv][ep] + i*16 + d*4);
                    f32x4 xj = *(const f32x4*)(sx[wv][ep] + j*16 + d*4);
                    f32x4 df = xi - xj;
                    rd += df * df;
                }
                #pragma unroll
                for (int kh = 0; kh < 2; ++kh) {
                    const int cb = kh*32 + q*8;
                    bf16_8 ha = *(const bf16_8*)(sHa[wv][ep] + i*LDB + cb);
                    bf16_8 hb = *(const bf16_8*)(sHb[wv][ep] + j*LDB + cb);
                    f32x4 wr0 = {0.f,0.f,0.f,0.f}, wr1 = {0.f,0.f,0.f,0.f};
                    #pragma unroll
                    for (int v = 0; v < 4; ++v) {
                        f32x4 wa = *(const f32x4*)(sWb[wv] + v*64 + cb);
                        f32x4 wb = *(const f32x4*)(sWb[wv] + v*64 + cb + 4);
                        wr0 += rd[v] * wa; wr1 += rd[v] * wb;
                    }
                    bf16_8 a;
                    #pragma unroll
                    for (int c = 0; c < 4; ++c)
                        a[c]   = (__bf16)silu_f((float)ha[c]   + (float)hb[c]   + wr0[c]);
                    #pragma unroll
                    for (int c = 0; c < 4; ++c)
                        a[4+c] = (__bf16)silu_f((float)ha[4+c] + (float)hb[4+c] + wr1[c]);
                    af[ep][kh] = a;
                }
            }
            // m = silu(s1@We2 + be2) -> per-env transposed staging
            #pragma unroll
            for (int ep = 0; ep < ENVW; ++ep) {
                __bf16* mT = &mstT[wv][ep][0];
                #pragma unroll
                for (int nt = 0; nt < 4; ++nt) {
                    f32x4 acc = {0.f,0.f,0.f,0.f};
                    acc = MFMA(af[ep][0], w2f[nt][0], acc);
                    acc = MFMA(af[ep][1], w2f[nt][1], acc);
                    bf16_4 mv;
                    #pragma unroll
                    for (int r = 0; r < 4; ++r) mv[r] = (__bf16)silu_f(acc[r] + be2q[nt]);
                    *(bf16_4*)(mT + (nt*16 + n16)*LDT + q*4) = mv;
                }
            }
            // wc = m@Wx + bx via MFMA (per env)
            #pragma unroll
            for (int ep = 0; ep < ENVW; ++ep) {
                const __bf16* mT = &mstT[wv][ep][0];
                bf16_8 aw0, aw1;
                #pragma unroll
                for (int j2 = 0; j2 < 8; ++j2) {
                    aw0[j2] = mT[(q*8 + j2)*LDT + n16];
                    aw1[j2] = mT[(32 + q*8 + j2)*LDT + n16];
                }
                f32x4 acc = {0.f,0.f,0.f,0.f};
                acc = MFMA(aw0, wxf[0], acc);
                acc = MFMA(aw1, wxf[1], acc);
                if (n16 < 4) {
                    #pragma unroll
                    for (int r = 0; r < 4; ++r) {
                        int row = t*16 + q*4 + r;
                        if (row < NEDGE) sWcB[wv][ep][row*4 + n16] = (__bf16)(acc[r] + bxv);
                    }
                }
            }
            // agg: lane = col; vectorized b64 reads
            #pragma unroll
            for (int ep = 0; ep < ENVW; ++ep) {
                const __bf16* mT = &mstT[wv][ep][0];
                bf16_4 c0 = *(const bf16_4*)(mT + lane*LDT + 0);
                #pragma unroll
                for (int el = 0; el < 4; ++el) agg[ep][(t*16 + el)/11] += (float)c0[el];
                if (t < 8) {
                    bf16_4 c1 = *(const bf16_4*)(mT + lane*LDT + 4);
                    bf16_4 c2 = *(const bf16_4*)(mT + lane*LDT + 8);
                    bf16_4 c3 = *(const bf16_4*)(mT + lane*LDT + 12);
                    #pragma unroll
                    for (int el = 0; el < 4; ++el) {
                        agg[ep][(t*16 + 4  + el)/11] += (float)c1[el];
                        agg[ep][(t*16 + 8  + el)/11] += (float)c2[el];
                        agg[ep][(t*16 + 12 + el)/11] += (float)c3[el];
                    }
                }
            }
        }
        // agg -> sHb (Hb dead after edge loop)
        #pragma unroll
        for (int ep = 0; ep < ENVW; ++ep)
            #pragma unroll
            for (int i = 0; i < NAG; ++i) sHb[wv][ep][i*LDB + lane] = (__bf16)agg[ep][i];

        // ---- xacc (pre-update x reads) ----
        float xn[ENVW][3];
        #pragma unroll
        for (int p = 0; p < 3; ++p) {
            int idx = p*64 + lane;
            int xi = idx / 12, dv = idx % 12, v = dv & 3;
            bool act = idx < 144;
            int xic = act ? xi : 0;
            #pragma unroll
            for (int ep = 0; ep < ENVW; ++ep) {
                float xiv = sx[wv][ep][xic*16 + dv];
                float acc = 0.f;
                #pragma unroll
                for (int j2 = 0; j2 < NAG; ++j2) {
                    int e2 = xic*11 + j2 - (j2 > xic ? 1 : 0);
                    e2 = (e2 < NEDGE) ? e2 : (NEDGE - 1);
                    float term = (xiv - sx[wv][ep][j2*16 + dv]) * (float)sWcB[wv][ep][e2*4 + v];
                    acc += (j2 == xic) ? 0.f : term;
                }
                xn[ep][p] = act ? (xiv + acc * (1.0f / 11.0f)) : 0.f;
            }
        }
        // ---- Wh1: t1 = silu([h,agg]@Wh1 + bh1) -> sHa ----
        {
            bf16_8 ah0[ENVW], ah1[ENVW], ag0[ENVW], ag1[ENVW];
            #pragma unroll
            for (int ep = 0; ep < ENVW; ++ep) {
                ah0[ep] = *(const bf16_8*)(sh[wv][ep]  + rowA*LDB + q*8);
                ah1[ep] = *(const bf16_8*)(sh[wv][ep]  + rowA*LDB + 32 + q*8);
                ag0[ep] = *(const bf16_8*)(sHb[wv][ep] + rowA*LDB + q*8);
                ag1[ep] = *(const bf16_8*)(sHb[wv][ep] + rowA*LDB + 32 + q*8);
            }
            #pragma unroll
            for (int nt = 0; nt < 4; ++nt) {
                bf16_8 b0 = loadB64(Wh1l, 0,  nt*16+n16, q);
                bf16_8 b1 = loadB64(Wh1l, 32, nt*16+n16, q);
                bf16_8 b2 = loadB64(Wh1l, 64, nt*16+n16, q);
                bf16_8 b3 = loadB64(Wh1l, 96, nt*16+n16, q);
                #pragma unroll
                for (int ep = 0; ep < ENVW; ++ep) {
                    f32x4 acc = {0.f,0.f,0.f,0.f};
                    acc = MFMA(ah0[ep], b0, acc); acc = MFMA(ah1[ep], b1, acc);
                    acc = MFMA(ag0[ep], b2, acc); acc = MFMA(ag1[ep], b3, acc);
                    #pragma unroll
                    for (int r = 0; r < 4; ++r) {
                        int row = q*4 + r;
                        if (row < NAG) sHa[wv][ep][row*LDB + nt*16+n16] = (__bf16)silu_f(acc[r] + bh1q[nt]);
                    }
                }
            }
        }
        // ---- x writeback; Wh2: h += t1@Wh2 + bh2 ----
        #pragma unroll
        for (int p = 0; p < 3; ++p) {
            int idx = p*64 + lane;
            if (idx < 144) {
                #pragma unroll
                for (int ep = 0; ep < ENVW; ++ep)
                    sx[wv][ep][(idx/12)*16 + idx%12] = xn[ep][p];
            }
        }
        {
            bf16_8 at0[ENVW], at1[ENVW];
            #pragma unroll
            for (int ep = 0; ep < ENVW; ++ep) {
                at0[ep] = *(const bf16_8*)(sHa[wv][ep] + rowA*LDB + q*8);
                at1[ep] = *(const bf16_8*)(sHa[wv][ep] + rowA*LDB + 32 + q*8);
            }
            #pragma unroll
            for (int nt = 0; nt < 4; ++nt) {
                bf16_8 b0 = loadB64(Wh2l, 0,  nt*16+n16, q);
                bf16_8 b1 = loadB64(Wh2l, 32, nt*16+n16, q);
                #pragma unroll
                for (int ep = 0; ep < ENVW; ++ep) {
                    f32x4 acc = {0.f,0.f,0.f,0.f};
                    acc = MFMA(at0[ep], b0, acc);
                    acc = MFMA(at1[ep], b1, acc);
                    #pragma unroll
                    for (int r = 0; r < 4; ++r) hC[ep][nt][r] += acc[r] + bh2q[nt];
                }
            }
            #pragma unroll
            for (int ep = 0; ep < ENVW; ++ep)
                #pragma unroll
                for (int nt = 0; nt < 4; ++nt)
                    #pragma unroll
                    for (int r = 0; r < 4; ++r) {
                        int row = q*4 + r;
                        if (row < NAG) sh[wv][ep][row*LDB + nt*16+n16] = (__bf16)hC[ep][nt][r];
                    }
        }
    }

    // ---- epilogue: mu only ----
    if (lane < NAG * 3) {
        int i = lane / 3, d = lane - i * 3;
        #pragma unroll
        for (int ep = 0; ep < ENVW; ++ep) {
            float mu = 0.f;
            #pragma unroll
            for (int v = 0; v < 4; ++v) mu += sx[wv][ep][i*16 + d*4 + v] * w_act[v];
            out[(env0 + ep) * (NAG*3) + lane] = mu;
        }
    }
}

extern "C" void kernel_launch(void* const* d_in, const int* in_sizes, int n_in,
                              void* d_out, int out_size, void* d_ws, size_t ws_size,
                              hipStream_t stream) {
    // inputs: h0,x0,W_embed,b_embed,We1,be1,We2,be2,Wx,bx,Wh1,bh1,Wh2,bh2,w_act,log_std,row,col
    const float* h0   = (const float*)d_in[0];
    const float* x0   = (const float*)d_in[1];
    const float* Wem  = (const float*)d_in[2];
    const float* bem  = (const float*)d_in[3];
    const float* We1  = (const float*)d_in[4];
    const float* be1  = (const float*)d_in[5];
    const float* We2  = (const float*)d_in[6];
    const float* be2  = (const float*)d_in[7];
    const float* Wx   = (const float*)d_in[8];
    const float* bx   = (const float*)d_in[9];
    const float* Wh1  = (const float*)d_in[10];
    const float* bh1  = (const float*)d_in[11];
    const float* Wh2  = (const float*)d_in[12];
    const float* bh2  = (const float*)d_in[13];
    const float* wact = (const float*)d_in[14];
    const float* lstd = (const float*)d_in[15];
    float* out = (float*)d_out;
    (void)d_ws; (void)ws_size;

    egnn16<<<dim3(NTH / (ENVW * NWAVE)), dim3(64 * NWAVE), 0, stream>>>(
        h0, x0, Wem, bem, We1, be1, We2, be2, Wx, bx,
        Wh1, bh1, Wh2, bh2, wact, lstd, out);
}

// Round 8
// 231.453 us; speedup vs baseline: 1.1329x; 1.0077x over previous
//
#include <hip/hip_runtime.h>

#define NAG 12
#define NTH 4096
#define NEDGE 132
#define ENVW 1    // R17: ONE env per wave — get COMBINED VGPR+AGPR under 256 -> 2 waves/SIMD
#define NWAVE 4   // waves per workgroup (independent, zero barriers)
#define LDB 72    // bf16 node-buffer row stride: 144 B, 16B-aligned, 2-way banks (free)
#define LDT 20    // mstT col stride (bf16): 40 B -> 8B-aligned b64, low-conflict

typedef __bf16 bf16_8 __attribute__((ext_vector_type(8)));
typedef __bf16 bf16_4 __attribute__((ext_vector_type(4)));
typedef float  f32x4  __attribute__((ext_vector_type(4)));

#define MFMA(a,b,c) __builtin_amdgcn_mfma_f32_16x16x32_bf16((a),(b),(c),0,0,0)

// ws layout:
//   frag region: 100 frags x 1024 B (64 lanes x 16 B)          [0, 102400)
//     0..3         : W_embed, nt
//     L = 4 + l*48 : We1a: L+nt*2+kh | We1b: L+8+nt*2+kh | We2: L+16+nt*2+kh
//                    Wh1: L+24+nt*4+ks | Wh2: L+40+nt*2+kh
//   bias region (fp32): float idx 25600 + ((l*4+w)*64+lane)*4  [102400, 110592)
//   bx region  (fp32): float idx 27648 + l*64 + lane           [110592, 111104)
#define WS_FRAGS 100
#define WS_BIAS_F32 25600
#define WS_BX_F32   27648
#define WS_BYTES 111104

__device__ __forceinline__ float silu_f(float z) {
    float e = __expf(-z);
    return z * __builtin_amdgcn_rcpf(1.0f + e);
}

// B-frag from fp32 row-major [K][64]: lane holds B[kbase+q*8+j][n]  (verified R2)
__device__ __forceinline__ bf16_8 loadB64(const float* __restrict__ W, int kbase, int n, int q) {
    bf16_8 b;
    #pragma unroll
    for (int j = 0; j < 8; ++j) b[j] = (__bf16)W[(kbase + q*8 + j) * 64 + n];
    return b;
}

// A-frag from 8 consecutive fp32 (16B-aligned)
__device__ __forceinline__ bf16_8 packA8(const float* S) {
    f32x4 u = *(const f32x4*)S, v = *(const f32x4*)(S + 4);
    bf16_8 a;
    a[0]=(__bf16)u.x; a[1]=(__bf16)u.y; a[2]=(__bf16)u.z; a[3]=(__bf16)u.w;
    a[4]=(__bf16)v.x; a[5]=(__bf16)v.y; a[6]=(__bf16)v.z; a[7]=(__bf16)v.w;
    return a;
}

// ---- prep: pack weight B-fragments (bf16) + bias vectors (fp32) into d_ws ----
__global__ __launch_bounds__(64) void prep_frags(
    const float* __restrict__ W_embed, const float* __restrict__ We1,
    const float* __restrict__ We2, const float* __restrict__ Wh1,
    const float* __restrict__ Wh2,
    const float* __restrict__ be1, const float* __restrict__ be2,
    const float* __restrict__ bh1, const float* __restrict__ bh2,
    const float* __restrict__ bx, __bf16* __restrict__ wsb)
{
    const int f = blockIdx.x, lane = threadIdx.x;
    const int q = lane >> 4, n16 = lane & 15;
    float* wsf = (float*)wsb;
    if (f < WS_FRAGS) {
        const float* src; int kbase, nbase;
        if (f < 4) { src = W_embed; kbase = 0; nbase = f * 16; }
        else {
            int g0 = f - 4, l = g0 / 48, r = g0 % 48;
            if      (r < 8)  { int nt=r>>1, kh=r&1;            src = We1 + l*NEDGE*64; kbase = kh*32;      nbase = nt*16; }
            else if (r < 16) { int rr=r-8,  nt=rr>>1, kh=rr&1; src = We1 + l*NEDGE*64; kbase = 64 + kh*32; nbase = nt*16; }
            else if (r < 24) { int rr=r-16, nt=rr>>1, kh=rr&1; src = We2 + l*64*64;    kbase = kh*32;      nbase = nt*16; }
            else if (r < 40) { int rr=r-24, nt=rr>>2, ks=rr&3; src = Wh1 + l*128*64;   kbase = ks*32;      nbase = nt*16; }
            else             { int rr=r-40, nt=rr>>1, kh=rr&1; src = Wh2 + l*64*64;    kbase = kh*32;      nbase = nt*16; }
        }
        bf16_8 b = loadB64(src, kbase, nbase + n16, q);
        *(bf16_8*)(wsb + (size_t)f * 512 + lane * 8) = b;
    } else if (f < WS_FRAGS + 8) {
        int f2 = f - WS_FRAGS, l = f2 >> 2, w = f2 & 3;
        const float* src = (w == 0 ? be1 : w == 1 ? be2 : w == 2 ? bh1 : bh2) + l * 64;
        f32x4 v = { src[n16], src[16 + n16], src[32 + n16], src[48 + n16] };
        *(f32x4*)(wsf + WS_BIAS_F32 + ((size_t)(l*4 + w) * 64 + lane) * 4) = v;
    } else {
        #pragma unroll
        for (int l = 0; l < 2; ++l)
            wsf[WS_BX_F32 + l*64 + lane] = (n16 < 4) ? bx[l*4 + n16] : 0.f;
    }
}

template<bool WS>
__device__ __forceinline__ bf16_8 frg(const __bf16* __restrict__ wsb, int fid,
                                      const float* __restrict__ src, int kbase, int n, int lane) {
    if (WS) return *(const bf16_8*)(wsb + (size_t)fid * 512 + lane * 8);
    else    return loadB64(src, kbase, n, (lane >> 4));
}

// ---- main: ONE ENV PER WAVE, 4 independent waves/WG, zero barriers ----
// R17 theory: the invariant ~11.3% occupancy (= ~1 wave/SIMD, wave lifetime
// ~65us, VALU duty ~45% == measured VALUBusy 41%) across R10-R16 is a
// UNIFIED-REGISTER-FILE cap: rocprof's VGPR_Count is arch-VGPRs only; on
// gfx950 VGPR+AGPR share one file, and every prior variant (228-236 arch +
// O(100) acc) lands just over the 256-combined boundary -> hard 1 wave/SIMD.
// This is the first theory consistent with ALL rounds, including R15's
// VGPR=160 null (acc pushed combined past 256) and R10's "residency tracks
// ~4/CU regardless" note. Fix: ENVW=1 halves per-wave live state -> combined
// ~200-220 <= 256 -> 2 waves/SIMD. TLP replaces the 2-env ILP. WS frag path
// kept (R16: direct loads cost +10us). Grid 1024 x 4 waves = 16 waves/CU
// attempted; LDS 40.3KB/WG -> 4 WGs/CU fit.
// NOTE (R3/R4/R8): occupancy-hint attributes cause allocator overshoot ->
// spill storms. Plain __launch_bounds__. FETCH_SIZE is the spill tripwire.
template<bool WS>
__global__ void __launch_bounds__(64 * NWAVE) egnn17(
    const float* __restrict__ h0, const float* __restrict__ x0,
    const float* __restrict__ W_embed, const float* __restrict__ b_embed,
    const float* __restrict__ We1, const float* __restrict__ be1,
    const float* __restrict__ We2, const float* __restrict__ be2,
    const float* __restrict__ Wx, const float* __restrict__ bx,
    const float* __restrict__ Wh1, const float* __restrict__ bh1,
    const float* __restrict__ Wh2, const float* __restrict__ bh2,
    const float* __restrict__ w_act, const float* __restrict__ log_std,
    const __bf16* __restrict__ wsb, float* __restrict__ out)
{
    // 40256 B total (4 x 10064) -> 4 WGs/CU = 16 waves/CU capacity
    __shared__ __align__(16) __bf16 sh  [NWAVE][ENVW][NAG * LDB];
    __shared__ __align__(16) __bf16 sHa [NWAVE][ENVW][NAG * LDB];
    __shared__ __align__(16) __bf16 sHb [NWAVE][ENVW][NAG * LDB];
    __shared__ __align__(16) __bf16 mstT[NWAVE][ENVW][64 * LDT];
    __shared__ __align__(16) float  sx  [NWAVE][ENVW][NAG * 16];
    __shared__ __align__(16) __bf16 sWcB[NWAVE][ENVW][NEDGE * 4];
    __shared__ __align__(16) float  sWb [NWAVE][4 * 64];   // per-wave copy (no barriers)

    const int tid  = threadIdx.x;
    const int wv   = tid >> 6;
    const int lane = tid & 63;
    const int q = lane >> 4, n16 = lane & 15;
    const int rowA = (n16 < NAG) ? n16 : (NAG - 1);
    const int env0 = (blockIdx.x * NWAVE + wv) * ENVW;
    const float* wsf = (const float*)wsb;

    // ---- constant log-prob half of the output ----
    if (lane < NAG * 3) {
        int d = lane % 3;
        float lp = -log_std[d] - 0.9189385332046727f;
        #pragma unroll
        for (int ep = 0; ep < ENVW; ++ep)
            out[NTH * NAG * 3 + (env0 + ep) * (NAG*3) + lane] = lp;
    }

    // ---- load x (this wave's envs: ENVW*144 floats contiguous) ----
    #pragma unroll
    for (int p = 0; p < (ENVW * 144 + 63) / 64; ++p) {
        int idx = p * 64 + lane;
        if (idx < ENVW * 144) {
            int ep = idx / 144, r2 = idx - ep * 144;
            sx[wv][ep][(r2 / 12) * 16 + r2 % 12] = x0[(env0) * NAG * 12 + idx];
        }
    }

    // ---- embed: h = h0 @ W_embed + b ----
    f32x4 hC[ENVW][4];
    {
        bf16_8 a[ENVW];
        #pragma unroll
        for (int ep = 0; ep < ENVW; ++ep)
            a[ep] = packA8(h0 + ((env0 + ep) * NAG + rowA) * 32 + q * 8);
        #pragma unroll
        for (int nt = 0; nt < 4; ++nt) {
            bf16_8 b = frg<WS>(wsb, nt, W_embed, 0, nt*16 + n16, lane);
            float bias = b_embed[nt*16 + n16];
            #pragma unroll
            for (int ep = 0; ep < ENVW; ++ep) {
                f32x4 acc = {0.f,0.f,0.f,0.f};
                acc = MFMA(a[ep], b, acc);
                #pragma unroll
                for (int r = 0; r < 4; ++r) acc[r] += bias;
                hC[ep][nt] = acc;
            }
        }
        #pragma unroll
        for (int ep = 0; ep < ENVW; ++ep)
            #pragma unroll
            for (int nt = 0; nt < 4; ++nt)
                #pragma unroll
                for (int r = 0; r < 4; ++r) {
                    int row = q*4 + r;
                    if (row < NAG) sh[wv][ep][row*LDB + nt*16 + n16] = (__bf16)hC[ep][nt][r];
                }
    }

    #pragma unroll 1
    for (int l = 0; l < 2; ++l) {
        const float* We1l = We1 + l * NEDGE * 64;
        const float* be1l = be1 + l * 64;
        const float* be2l = be2 + l * 64;
        const float* Wxl  = Wx  + l * 64 * 4;
        const float* bxl  = bx  + l * 4;
        const float* We2l = We2 + l * 64 * 64;
        const float* Wh1l = Wh1 + l * 128 * 64;
        const float* bh1l = bh1 + l * 64;
        const float* Wh2l = Wh2 + l * 64 * 64;
        const float* bh2l = bh2 + l * 64;
        const int L = 4 + l * 48;

        f32x4 be1q, be2q, bh1q, bh2q;
        float bxv;
        if (WS) {
            const float* bb = wsf + WS_BIAS_F32 + (size_t)(l*4) * 256 + lane * 4;
            be1q = *(const f32x4*)(bb);
            be2q = *(const f32x4*)(bb + 256);
            bh1q = *(const f32x4*)(bb + 512);
            bh2q = *(const f32x4*)(bb + 768);
            bxv  = wsf[WS_BX_F32 + l*64 + lane];
        } else {
            #pragma unroll
            for (int nt = 0; nt < 4; ++nt) {
                be1q[nt] = be1l[nt*16+n16]; be2q[nt] = be2l[nt*16+n16];
                bh1q[nt] = bh1l[nt*16+n16]; bh2q[nt] = bh2l[nt*16+n16];
            }
            bxv = (n16 < 4) ? bxl[n16] : 0.f;
        }

        // ---- Stage A: Ha/Hb ----
        {
            bf16_8 a0[ENVW], a1[ENVW];
            #pragma unroll
            for (int ep = 0; ep < ENVW; ++ep) {
                a0[ep] = *(const bf16_8*)(sh[wv][ep] + rowA*LDB + q*8);
                a1[ep] = *(const bf16_8*)(sh[wv][ep] + rowA*LDB + 32 + q*8);
            }
            #pragma unroll
            for (int nt = 0; nt < 4; ++nt) {
                bf16_8 b0 = frg<WS>(wsb, L+nt*2+0,   We1l, 0,  nt*16+n16, lane);
                bf16_8 b1 = frg<WS>(wsb, L+nt*2+1,   We1l, 32, nt*16+n16, lane);
                bf16_8 c0 = frg<WS>(wsb, L+8+nt*2+0, We1l, 64, nt*16+n16, lane);
                bf16_8 c1 = frg<WS>(wsb, L+8+nt*2+1, We1l, 96, nt*16+n16, lane);
                #pragma unroll
                for (int ep = 0; ep < ENVW; ++ep) {
                    f32x4 aA = {0.f,0.f,0.f,0.f}, aB = {0.f,0.f,0.f,0.f};
                    aA = MFMA(a0[ep], b0, aA); aA = MFMA(a1[ep], b1, aA);
                    aB = MFMA(a0[ep], c0, aB); aB = MFMA(a1[ep], c1, aB);
                    #pragma unroll
                    for (int r = 0; r < 4; ++r) {
                        int row = q*4 + r;
                        if (row < NAG) {
                            sHa[wv][ep][row*LDB + nt*16+n16] = (__bf16)(aA[r] + be1q[nt]);
                            sHb[wv][ep][row*LDB + nt*16+n16] = (__bf16)aB[r];
                        }
                    }
                }
            }
        }
        #pragma unroll
        for (int p = 0; p < 4; ++p) sWb[wv][p*64 + lane] = We1l[(128+p)*64 + lane];

        // ---- Edge stage: 9 M-tiles ----
        float agg[ENVW][NAG];
        #pragma unroll
        for (int ep = 0; ep < ENVW; ++ep)
            #pragma unroll
            for (int i = 0; i < NAG; ++i) agg[ep][i] = 0.f;
        bf16_8 w2f[4][2], wxf[2];
        #pragma unroll
        for (int nt = 0; nt < 4; ++nt) {
            w2f[nt][0] = frg<WS>(wsb, L+16+nt*2+0, We2l, 0,  nt*16+n16, lane);
            w2f[nt][1] = frg<WS>(wsb, L+16+nt*2+1, We2l, 32, nt*16+n16, lane);
        }
        #pragma unroll
        for (int kh = 0; kh < 2; ++kh) {
            bf16_8 b;
            #pragma unroll
            for (int j2 = 0; j2 < 8; ++j2)
                b[j2] = (n16 < 4) ? (__bf16)Wxl[(kh*32 + q*8 + j2)*4 + n16] : (__bf16)0.f;
            wxf[kh] = b;
        }

        #pragma unroll
        for (int t = 0; t < 9; ++t) {
            const int e  = t*16 + n16;
            const int ec = (e < NEDGE) ? e : (NEDGE - 1);
            const int i  = ec / 11;
            const int jj = ec - i * 11;
            const int j  = jj + (jj >= i);
            bf16_8 af[ENVW][2];
            #pragma unroll
            for (int ep = 0; ep < ENVW; ++ep) {
                // radial recomputed on the fly; same d-order -> identical fp
                f32x4 rd = {0.f,0.f,0.f,0.f};
                #pragma unroll
                for (int d = 0; d < 3; ++d) {
                    f32x4 xi = *(const f32x4*)(sx[wv][ep] + i*16 + d*4);
                    f32x4 xj = *(const f32x4*)(sx[wv][ep] + j*16 + d*4);
                    f32x4 df = xi - xj;
                    rd += df * df;
                }
                #pragma unroll
                for (int kh = 0; kh < 2; ++kh) {
                    const int cb = kh*32 + q*8;
                    bf16_8 ha = *(const bf16_8*)(sHa[wv][ep] + i*LDB + cb);
                    bf16_8 hb = *(const bf16_8*)(sHb[wv][ep] + j*LDB + cb);
                    f32x4 wr0 = {0.f,0.f,0.f,0.f}, wr1 = {0.f,0.f,0.f,0.f};
                    #pragma unroll
                    for (int v = 0; v < 4; ++v) {
                        f32x4 wa = *(const f32x4*)(sWb[wv] + v*64 + cb);
                        f32x4 wb = *(const f32x4*)(sWb[wv] + v*64 + cb + 4);
                        wr0 += rd[v] * wa; wr1 += rd[v] * wb;
                    }
                    bf16_8 a;
                    #pragma unroll
                    for (int c = 0; c < 4; ++c)
                        a[c]   = (__bf16)silu_f((float)ha[c]   + (float)hb[c]   + wr0[c]);
                    #pragma unroll
                    for (int c = 0; c < 4; ++c)
                        a[4+c] = (__bf16)silu_f((float)ha[4+c] + (float)hb[4+c] + wr1[c]);
                    af[ep][kh] = a;
                }
            }
            // m = silu(s1@We2 + be2) -> transposed staging
            #pragma unroll
            for (int ep = 0; ep < ENVW; ++ep) {
                __bf16* mT = &mstT[wv][ep][0];
                #pragma unroll
                for (int nt = 0; nt < 4; ++nt) {
                    f32x4 acc = {0.f,0.f,0.f,0.f};
                    acc = MFMA(af[ep][0], w2f[nt][0], acc);
                    acc = MFMA(af[ep][1], w2f[nt][1], acc);
                    bf16_4 mv;
                    #pragma unroll
                    for (int r = 0; r < 4; ++r) mv[r] = (__bf16)silu_f(acc[r] + be2q[nt]);
                    *(bf16_4*)(mT + (nt*16 + n16)*LDT + q*4) = mv;
                }
            }
            // wc = m@Wx + bx via MFMA
            #pragma unroll
            for (int ep = 0; ep < ENVW; ++ep) {
                const __bf16* mT = &mstT[wv][ep][0];
                bf16_8 aw0, aw1;
                #pragma unroll
                for (int j2 = 0; j2 < 8; ++j2) {
                    aw0[j2] = mT[(q*8 + j2)*LDT + n16];
                    aw1[j2] = mT[(32 + q*8 + j2)*LDT + n16];
                }
                f32x4 acc = {0.f,0.f,0.f,0.f};
                acc = MFMA(aw0, wxf[0], acc);
                acc = MFMA(aw1, wxf[1], acc);
                if (n16 < 4) {
                    #pragma unroll
                    for (int r = 0; r < 4; ++r) {
                        int row = t*16 + q*4 + r;
                        if (row < NEDGE) sWcB[wv][ep][row*4 + n16] = (__bf16)(acc[r] + bxv);
                    }
                }
            }
            // agg: lane = col; vectorized b64 reads
            #pragma unroll
            for (int ep = 0; ep < ENVW; ++ep) {
                const __bf16* mT = &mstT[wv][ep][0];
                bf16_4 c0 = *(const bf16_4*)(mT + lane*LDT + 0);
                #pragma unroll
                for (int el = 0; el < 4; ++el) agg[ep][(t*16 + el)/11] += (float)c0[el];
                if (t < 8) {
                    bf16_4 c1 = *(const bf16_4*)(mT + lane*LDT + 4);
                    bf16_4 c2 = *(const bf16_4*)(mT + lane*LDT + 8);
                    bf16_4 c3 = *(const bf16_4*)(mT + lane*LDT + 12);
                    #pragma unroll
                    for (int el = 0; el < 4; ++el) {
                        agg[ep][(t*16 + 4  + el)/11] += (float)c1[el];
                        agg[ep][(t*16 + 8  + el)/11] += (float)c2[el];
                        agg[ep][(t*16 + 12 + el)/11] += (float)c3[el];
                    }
                }
            }
        }
        // agg -> sHb (Hb dead after edge loop)
        #pragma unroll
        for (int ep = 0; ep < ENVW; ++ep)
            #pragma unroll
            for (int i = 0; i < NAG; ++i) sHb[wv][ep][i*LDB + lane] = (__bf16)agg[ep][i];

        // ---- xacc (pre-update x reads) ----
        float xn[ENVW][3];
        #pragma unroll
        for (int p = 0; p < 3; ++p) {
            int idx = p*64 + lane;
            int xi = idx / 12, dv = idx % 12, v = dv & 3;
            bool act = idx < 144;
            int xic = act ? xi : 0;
            #pragma unroll
            for (int ep = 0; ep < ENVW; ++ep) {
                float xiv = sx[wv][ep][xic*16 + dv];
                float acc = 0.f;
                #pragma unroll
                for (int j2 = 0; j2 < NAG; ++j2) {
                    int e2 = xic*11 + j2 - (j2 > xic ? 1 : 0);
                    e2 = (e2 < NEDGE) ? e2 : (NEDGE - 1);
                    float term = (xiv - sx[wv][ep][j2*16 + dv]) * (float)sWcB[wv][ep][e2*4 + v];
                    acc += (j2 == xic) ? 0.f : term;
                }
                xn[ep][p] = act ? (xiv + acc * (1.0f / 11.0f)) : 0.f;
            }
        }
        // ---- Wh1: t1 = silu([h,agg]@Wh1 + bh1) -> sHa ----
        {
            bf16_8 ah0[ENVW], ah1[ENVW], ag0[ENVW], ag1[ENVW];
            #pragma unroll
            for (int ep = 0; ep < ENVW; ++ep) {
                ah0[ep] = *(const bf16_8*)(sh[wv][ep]  + rowA*LDB + q*8);
                ah1[ep] = *(const bf16_8*)(sh[wv][ep]  + rowA*LDB + 32 + q*8);
                ag0[ep] = *(const bf16_8*)(sHb[wv][ep] + rowA*LDB + q*8);
                ag1[ep] = *(const bf16_8*)(sHb[wv][ep] + rowA*LDB + 32 + q*8);
            }
            #pragma unroll
            for (int nt = 0; nt < 4; ++nt) {
                bf16_8 b0 = frg<WS>(wsb, L+24+nt*4+0, Wh1l, 0,  nt*16+n16, lane);
                bf16_8 b1 = frg<WS>(wsb, L+24+nt*4+1, Wh1l, 32, nt*16+n16, lane);
                bf16_8 b2 = frg<WS>(wsb, L+24+nt*4+2, Wh1l, 64, nt*16+n16, lane);
                bf16_8 b3 = frg<WS>(wsb, L+24+nt*4+3, Wh1l, 96, nt*16+n16, lane);
                #pragma unroll
                for (int ep = 0; ep < ENVW; ++ep) {
                    f32x4 acc = {0.f,0.f,0.f,0.f};
                    acc = MFMA(ah0[ep], b0, acc); acc = MFMA(ah1[ep], b1, acc);
                    acc = MFMA(ag0[ep], b2, acc); acc = MFMA(ag1[ep], b3, acc);
                    #pragma unroll
                    for (int r = 0; r < 4; ++r) {
                        int row = q*4 + r;
                        if (row < NAG) sHa[wv][ep][row*LDB + nt*16+n16] = (__bf16)silu_f(acc[r] + bh1q[nt]);
                    }
                }
            }
        }
        // ---- x writeback; Wh2: h += t1@Wh2 + bh2 ----
        #pragma unroll
        for (int p = 0; p < 3; ++p) {
            int idx = p*64 + lane;
            if (idx < 144) {
                #pragma unroll
                for (int ep = 0; ep < ENVW; ++ep)
                    sx[wv][ep][(idx/12)*16 + idx%12] = xn[ep][p];
            }
        }
        {
            bf16_8 at0[ENVW], at1[ENVW];
            #pragma unroll
            for (int ep = 0; ep < ENVW; ++ep) {
                at0[ep] = *(const bf16_8*)(sHa[wv][ep] + rowA*LDB + q*8);
                at1[ep] = *(const bf16_8*)(sHa[wv][ep] + rowA*LDB + 32 + q*8);
            }
            #pragma unroll
            for (int nt = 0; nt < 4; ++nt) {
                bf16_8 b0 = frg<WS>(wsb, L+40+nt*2+0, Wh2l, 0,  nt*16+n16, lane);
                bf16_8 b1 = frg<WS>(wsb, L+40+nt*2+1, Wh2l, 32, nt*16+n16, lane);
                #pragma unroll
                for (int ep = 0; ep < ENVW; ++ep) {
                    f32x4 acc = {0.f,0.f,0.f,0.f};
                    acc = MFMA(at0[ep], b0, acc);
                    acc = MFMA(at1[ep], b1, acc);
                    #pragma unroll
                    for (int r = 0; r < 4; ++r) hC[ep][nt][r] += acc[r] + bh2q[nt];
                }
            }
            #pragma unroll
            for (int ep = 0; ep < ENVW; ++ep)
                #pragma unroll
                for (int nt = 0; nt < 4; ++nt)
                    #pragma unroll
                    for (int r = 0; r < 4; ++r) {
                        int row = q*4 + r;
                        if (row < NAG) sh[wv][ep][row*LDB + nt*16+n16] = (__bf16)hC[ep][nt][r];
                    }
        }
    }

    // ---- epilogue: mu only ----
    if (lane < NAG * 3) {
        int i = lane / 3, d = lane - i * 3;
        #pragma unroll
        for (int ep = 0; ep < ENVW; ++ep) {
            float mu = 0.f;
            #pragma unroll
            for (int v = 0; v < 4; ++v) mu += sx[wv][ep][i*16 + d*4 + v] * w_act[v];
            out[(env0 + ep) * (NAG*3) + lane] = mu;
        }
    }
}

extern "C" void kernel_launch(void* const* d_in, const int* in_sizes, int n_in,
                              void* d_out, int out_size, void* d_ws, size_t ws_size,
                              hipStream_t stream) {
    // inputs: h0,x0,W_embed,b_embed,We1,be1,We2,be2,Wx,bx,Wh1,bh1,Wh2,bh2,w_act,log_std,row,col
    const float* h0   = (const float*)d_in[0];
    const float* x0   = (const float*)d_in[1];
    const float* Wem  = (const float*)d_in[2];
    const float* bem  = (const float*)d_in[3];
    const float* We1  = (const float*)d_in[4];
    const float* be1  = (const float*)d_in[5];
    const float* We2  = (const float*)d_in[6];
    const float* be2  = (const float*)d_in[7];
    const float* Wx   = (const float*)d_in[8];
    const float* bx   = (const float*)d_in[9];
    const float* Wh1  = (const float*)d_in[10];
    const float* bh1  = (const float*)d_in[11];
    const float* Wh2  = (const float*)d_in[12];
    const float* bh2  = (const float*)d_in[13];
    const float* wact = (const float*)d_in[14];
    const float* lstd = (const float*)d_in[15];
    float* out = (float*)d_out;

    if (ws_size >= (size_t)WS_BYTES) {
        prep_frags<<<dim3(WS_FRAGS + 9), dim3(64), 0, stream>>>(
            Wem, We1, We2, Wh1, Wh2, be1, be2, bh1, bh2, bx, (__bf16*)d_ws);
        egnn17<true><<<dim3(NTH / (ENVW * NWAVE)), dim3(64 * NWAVE), 0, stream>>>(
            h0, x0, Wem, bem, We1, be1, We2, be2, Wx, bx,
            Wh1, bh1, Wh2, bh2, wact, lstd, (const __bf16*)d_ws, out);
    } else {
        egnn17<false><<<dim3(NTH / (ENVW * NWAVE)), dim3(64 * NWAVE), 0, stream>>>(
            h0, x0, Wem, bem, We1, be1, We2, be2, Wx, bx,
            Wh1, bh1, Wh2, bh2, wact, lstd, nullptr, out);
    }
}

// Round 9
// 220.996 us; speedup vs baseline: 1.1865x; 1.0473x over previous
//
#include <hip/hip_runtime.h>

#define NAG 12
#define NTH 4096
#define NEDGE 132
#define ENVW 2    // envs per wave (proven best: R12's 4 spilled, R17's 1 lost amortization)
#define NWAVE 4   // waves per workgroup (R13 best: atomic co-residency + I$ co-locality)
#define LDB 72    // bf16 node-buffer row stride: 144 B, 16B-aligned, 2-way banks (free)
#define LDT 20    // mstT col stride (bf16): 40 B -> 8B-aligned b64, low-conflict

typedef __bf16 bf16_8 __attribute__((ext_vector_type(8)));
typedef __bf16 bf16_4 __attribute__((ext_vector_type(4)));
typedef float  f32x4  __attribute__((ext_vector_type(4)));

#define MFMA(a,b,c) __builtin_amdgcn_mfma_f32_16x16x32_bf16((a),(b),(c),0,0,0)

// ws layout:
//   frag region: 100 frags x 1024 B (64 lanes x 16 B)          [0, 102400)
//     0..3         : W_embed, nt
//     L = 4 + l*48 : We1a: L+nt*2+kh | We1b: L+8+nt*2+kh | We2: L+16+nt*2+kh
//                    Wh1: L+24+nt*4+ks | Wh2: L+40+nt*2+kh
//   bias region (fp32): float idx 25600 + ((l*4+w)*64+lane)*4  [102400, 110592)
//   bx region  (fp32): float idx 27648 + l*64 + lane           [110592, 111104)
#define WS_FRAGS 100
#define WS_BIAS_F32 25600
#define WS_BX_F32   27648
#define WS_BYTES 111104

__device__ __forceinline__ float silu_f(float z) {
    float e = __expf(-z);
    return z * __builtin_amdgcn_rcpf(1.0f + e);
}

// B-frag from fp32 row-major [K][64]: lane holds B[kbase+q*8+j][n]  (verified R2)
__device__ __forceinline__ bf16_8 loadB64(const float* __restrict__ W, int kbase, int n, int q) {
    bf16_8 b;
    #pragma unroll
    for (int j = 0; j < 8; ++j) b[j] = (__bf16)W[(kbase + q*8 + j) * 64 + n];
    return b;
}

// A-frag from 8 consecutive fp32 (16B-aligned)
__device__ __forceinline__ bf16_8 packA8(const float* S) {
    f32x4 u = *(const f32x4*)S, v = *(const f32x4*)(S + 4);
    bf16_8 a;
    a[0]=(__bf16)u.x; a[1]=(__bf16)u.y; a[2]=(__bf16)u.z; a[3]=(__bf16)u.w;
    a[4]=(__bf16)v.x; a[5]=(__bf16)v.y; a[6]=(__bf16)v.z; a[7]=(__bf16)v.w;
    return a;
}

// ---- prep: pack weight B-fragments (bf16) + bias vectors (fp32) into d_ws ----
__global__ __launch_bounds__(64) void prep_frags(
    const float* __restrict__ W_embed, const float* __restrict__ We1,
    const float* __restrict__ We2, const float* __restrict__ Wh1,
    const float* __restrict__ Wh2,
    const float* __restrict__ be1, const float* __restrict__ be2,
    const float* __restrict__ bh1, const float* __restrict__ bh2,
    const float* __restrict__ bx, __bf16* __restrict__ wsb)
{
    const int f = blockIdx.x, lane = threadIdx.x;
    const int q = lane >> 4, n16 = lane & 15;
    float* wsf = (float*)wsb;
    if (f < WS_FRAGS) {
        const float* src; int kbase, nbase;
        if (f < 4) { src = W_embed; kbase = 0; nbase = f * 16; }
        else {
            int g0 = f - 4, l = g0 / 48, r = g0 % 48;
            if      (r < 8)  { int nt=r>>1, kh=r&1;            src = We1 + l*NEDGE*64; kbase = kh*32;      nbase = nt*16; }
            else if (r < 16) { int rr=r-8,  nt=rr>>1, kh=rr&1; src = We1 + l*NEDGE*64; kbase = 64 + kh*32; nbase = nt*16; }
            else if (r < 24) { int rr=r-16, nt=rr>>1, kh=rr&1; src = We2 + l*64*64;    kbase = kh*32;      nbase = nt*16; }
            else if (r < 40) { int rr=r-24, nt=rr>>2, ks=rr&3; src = Wh1 + l*128*64;   kbase = ks*32;      nbase = nt*16; }
            else             { int rr=r-40, nt=rr>>1, kh=rr&1; src = Wh2 + l*64*64;    kbase = kh*32;      nbase = nt*16; }
        }
        bf16_8 b = loadB64(src, kbase, nbase + n16, q);
        *(bf16_8*)(wsb + (size_t)f * 512 + lane * 8) = b;
    } else if (f < WS_FRAGS + 8) {
        int f2 = f - WS_FRAGS, l = f2 >> 2, w = f2 & 3;
        const float* src = (w == 0 ? be1 : w == 1 ? be2 : w == 2 ? bh1 : bh2) + l * 64;
        f32x4 v = { src[n16], src[16 + n16], src[32 + n16], src[48 + n16] };
        *(f32x4*)(wsf + WS_BIAS_F32 + ((size_t)(l*4 + w) * 64 + lane) * 4) = v;
    } else {
        #pragma unroll
        for (int l = 0; l < 2; ++l)
            wsf[WS_BX_F32 + l*64 + lane] = (n16 < 4) ? bx[l*4 + n16] : 0.f;
    }
}

template<bool WS>
__device__ __forceinline__ bf16_8 frg(const __bf16* __restrict__ wsb, int fid,
                                      const float* __restrict__ src, int kbase, int n, int lane) {
    if (WS) return *(const bf16_8*)(wsb + (size_t)fid * 512 + lane * 8);
    else    return loadB64(src, kbase, n, (lane >> 4));
}

// ---- main: R13 structure restored (best: 145.4us) + instruction diet ----
// R18: seven falsified theories (LDS residency R11, reg/ILP R12, atomic wave
// alloc R13, I$ R14, chain-split R15, prep-removal R16, unified-regfile R17 --
// VGPR=160 still pinned at 11.3% occupancy). Surviving model: time ~ total
// dynamic VALU instruction count at a fixed external effective issue rate
// (~3.6 live waves/CU, ~41% duty; every round's delta tracks its instruction
// delta). So: restore the best structure (R13) and shave instructions:
//   (1) sWb wa/wb LDS reads hoisted out of the ep loop (env-invariant);
//   (2) s_setprio(1) around MFMA-dense m-stage + Wh1 clusters (T5 regime:
//       independent phase-staggered waves, the attn-like +4-7% case).
// NOTE (R3/R4/R8): occupancy-hint attributes cause allocator overshoot ->
// spill storms. Plain __launch_bounds__. FETCH_SIZE is the spill tripwire.
template<bool WS>
__global__ void __launch_bounds__(64 * NWAVE) egnn18(
    const float* __restrict__ h0, const float* __restrict__ x0,
    const float* __restrict__ W_embed, const float* __restrict__ b_embed,
    const float* __restrict__ We1, const float* __restrict__ be1,
    const float* __restrict__ We2, const float* __restrict__ be2,
    const float* __restrict__ Wx, const float* __restrict__ bx,
    const float* __restrict__ Wh1, const float* __restrict__ bh1,
    const float* __restrict__ Wh2, const float* __restrict__ bh2,
    const float* __restrict__ w_act, const float* __restrict__ log_std,
    const __bf16* __restrict__ wsb, float* __restrict__ out)
{
    // 80640 B total (4 x 20160) -> 2 blocks/CU = 8 waves/CU capacity
    __shared__ __align__(16) __bf16 sh  [NWAVE][ENVW][NAG * LDB];
    __shared__ __align__(16) __bf16 sHa [NWAVE][ENVW][NAG * LDB];
    __shared__ __align__(16) __bf16 sHb [NWAVE][ENVW][NAG * LDB];
    __shared__ __align__(16) __bf16 mstT[NWAVE][ENVW][64 * LDT];
    __shared__ __align__(16) float  sx  [NWAVE][ENVW][NAG * 16];
    __shared__ __align__(16) __bf16 sWcB[NWAVE][ENVW][NEDGE * 4];
    __shared__ __align__(16) float  sWb [NWAVE][4 * 64];   // per-wave copy (no barriers)

    const int tid  = threadIdx.x;
    const int wv   = tid >> 6;
    const int lane = tid & 63;
    const int q = lane >> 4, n16 = lane & 15;
    const int rowA = (n16 < NAG) ? n16 : (NAG - 1);
    const int env0 = (blockIdx.x * NWAVE + wv) * ENVW;
    const float* wsf = (const float*)wsb;

    // ---- constant log-prob half of the output ----
    if (lane < NAG * 3) {
        int d = lane % 3;
        float lp = -log_std[d] - 0.9189385332046727f;
        #pragma unroll
        for (int ep = 0; ep < ENVW; ++ep)
            out[NTH * NAG * 3 + (env0 + ep) * (NAG*3) + lane] = lp;
    }

    // ---- load x (this wave's envs: ENVW*144 floats contiguous) ----
    #pragma unroll
    for (int p = 0; p < (ENVW * 144 + 63) / 64; ++p) {
        int idx = p * 64 + lane;
        if (idx < ENVW * 144) {
            int ep = idx / 144, r2 = idx - ep * 144;
            sx[wv][ep][(r2 / 12) * 16 + r2 % 12] = x0[(env0) * NAG * 12 + idx];
        }
    }

    // ---- embed: h = h0 @ W_embed + b ----
    f32x4 hC[ENVW][4];
    {
        bf16_8 a[ENVW];
        #pragma unroll
        for (int ep = 0; ep < ENVW; ++ep)
            a[ep] = packA8(h0 + ((env0 + ep) * NAG + rowA) * 32 + q * 8);
        #pragma unroll
        for (int nt = 0; nt < 4; ++nt) {
            bf16_8 b = frg<WS>(wsb, nt, W_embed, 0, nt*16 + n16, lane);
            float bias = b_embed[nt*16 + n16];
            #pragma unroll
            for (int ep = 0; ep < ENVW; ++ep) {
                f32x4 acc = {0.f,0.f,0.f,0.f};
                acc = MFMA(a[ep], b, acc);
                #pragma unroll
                for (int r = 0; r < 4; ++r) acc[r] += bias;
                hC[ep][nt] = acc;
            }
        }
        #pragma unroll
        for (int ep = 0; ep < ENVW; ++ep)
            #pragma unroll
            for (int nt = 0; nt < 4; ++nt)
                #pragma unroll
                for (int r = 0; r < 4; ++r) {
                    int row = q*4 + r;
                    if (row < NAG) sh[wv][ep][row*LDB + nt*16 + n16] = (__bf16)hC[ep][nt][r];
                }
    }

    #pragma unroll 1
    for (int l = 0; l < 2; ++l) {
        const float* We1l = We1 + l * NEDGE * 64;
        const float* be1l = be1 + l * 64;
        const float* be2l = be2 + l * 64;
        const float* Wxl  = Wx  + l * 64 * 4;
        const float* bxl  = bx  + l * 4;
        const float* We2l = We2 + l * 64 * 64;
        const float* Wh1l = Wh1 + l * 128 * 64;
        const float* bh1l = bh1 + l * 64;
        const float* Wh2l = Wh2 + l * 64 * 64;
        const float* bh2l = bh2 + l * 64;
        const int L = 4 + l * 48;

        f32x4 be1q, be2q, bh1q, bh2q;
        float bxv;
        if (WS) {
            const float* bb = wsf + WS_BIAS_F32 + (size_t)(l*4) * 256 + lane * 4;
            be1q = *(const f32x4*)(bb);
            be2q = *(const f32x4*)(bb + 256);
            bh1q = *(const f32x4*)(bb + 512);
            bh2q = *(const f32x4*)(bb + 768);
            bxv  = wsf[WS_BX_F32 + l*64 + lane];
        } else {
            #pragma unroll
            for (int nt = 0; nt < 4; ++nt) {
                be1q[nt] = be1l[nt*16+n16]; be2q[nt] = be2l[nt*16+n16];
                bh1q[nt] = bh1l[nt*16+n16]; bh2q[nt] = bh2l[nt*16+n16];
            }
            bxv = (n16 < 4) ? bxl[n16] : 0.f;
        }

        // ---- Stage A: Ha/Hb ----
        {
            bf16_8 a0[ENVW], a1[ENVW];
            #pragma unroll
            for (int ep = 0; ep < ENVW; ++ep) {
                a0[ep] = *(const bf16_8*)(sh[wv][ep] + rowA*LDB + q*8);
                a1[ep] = *(const bf16_8*)(sh[wv][ep] + rowA*LDB + 32 + q*8);
            }
            #pragma unroll
            for (int nt = 0; nt < 4; ++nt) {
                bf16_8 b0 = frg<WS>(wsb, L+nt*2+0,   We1l, 0,  nt*16+n16, lane);
                bf16_8 b1 = frg<WS>(wsb, L+nt*2+1,   We1l, 32, nt*16+n16, lane);
                bf16_8 c0 = frg<WS>(wsb, L+8+nt*2+0, We1l, 64, nt*16+n16, lane);
                bf16_8 c1 = frg<WS>(wsb, L+8+nt*2+1, We1l, 96, nt*16+n16, lane);
                #pragma unroll
                for (int ep = 0; ep < ENVW; ++ep) {
                    f32x4 aA = {0.f,0.f,0.f,0.f}, aB = {0.f,0.f,0.f,0.f};
                    aA = MFMA(a0[ep], b0, aA); aA = MFMA(a1[ep], b1, aA);
                    aB = MFMA(a0[ep], c0, aB); aB = MFMA(a1[ep], c1, aB);
                    #pragma unroll
                    for (int r = 0; r < 4; ++r) {
                        int row = q*4 + r;
                        if (row < NAG) {
                            sHa[wv][ep][row*LDB + nt*16+n16] = (__bf16)(aA[r] + be1q[nt]);
                            sHb[wv][ep][row*LDB + nt*16+n16] = (__bf16)aB[r];
                        }
                    }
                }
            }
        }
        #pragma unroll
        for (int p = 0; p < 4; ++p) sWb[wv][p*64 + lane] = We1l[(128+p)*64 + lane];

        // ---- Edge stage: 9 M-tiles x ENVW envs interleaved ----
        float agg[ENVW][NAG];
        #pragma unroll
        for (int ep = 0; ep < ENVW; ++ep)
            #pragma unroll
            for (int i = 0; i < NAG; ++i) agg[ep][i] = 0.f;
        bf16_8 w2f[4][2], wxf[2];
        #pragma unroll
        for (int nt = 0; nt < 4; ++nt) {
            w2f[nt][0] = frg<WS>(wsb, L+16+nt*2+0, We2l, 0,  nt*16+n16, lane);
            w2f[nt][1] = frg<WS>(wsb, L+16+nt*2+1, We2l, 32, nt*16+n16, lane);
        }
        #pragma unroll
        for (int kh = 0; kh < 2; ++kh) {
            bf16_8 b;
            #pragma unroll
            for (int j2 = 0; j2 < 8; ++j2)
                b[j2] = (n16 < 4) ? (__bf16)Wxl[(kh*32 + q*8 + j2)*4 + n16] : (__bf16)0.f;
            wxf[kh] = b;
        }

        #pragma unroll
        for (int t = 0; t < 9; ++t) {
            // env-independent index math (amortized over both envs)
            const int e  = t*16 + n16;
            const int ec = (e < NEDGE) ? e : (NEDGE - 1);
            const int i  = ec / 11;
            const int jj = ec - i * 11;
            const int j  = jj + (jj >= i);
            // radial per env (same d-order -> identical fp)
            f32x4 rdv[ENVW];
            #pragma unroll
            for (int ep = 0; ep < ENVW; ++ep) {
                f32x4 rd = {0.f,0.f,0.f,0.f};
                #pragma unroll
                for (int d = 0; d < 3; ++d) {
                    f32x4 xi = *(const f32x4*)(sx[wv][ep] + i*16 + d*4);
                    f32x4 xj = *(const f32x4*)(sx[wv][ep] + j*16 + d*4);
                    f32x4 df = xi - xj;
                    rd += df * df;
                }
                rdv[ep] = rd;
            }
            // A-frags: wa/wb hoisted to kh level (env-invariant)
            bf16_8 af[ENVW][2];
            #pragma unroll
            for (int kh = 0; kh < 2; ++kh) {
                const int cb = kh*32 + q*8;
                f32x4 wa[4], wb[4];
                #pragma unroll
                for (int v = 0; v < 4; ++v) {
                    wa[v] = *(const f32x4*)(sWb[wv] + v*64 + cb);
                    wb[v] = *(const f32x4*)(sWb[wv] + v*64 + cb + 4);
                }
                #pragma unroll
                for (int ep = 0; ep < ENVW; ++ep) {
                    bf16_8 ha = *(const bf16_8*)(sHa[wv][ep] + i*LDB + cb);
                    bf16_8 hb = *(const bf16_8*)(sHb[wv][ep] + j*LDB + cb);
                    f32x4 wr0 = {0.f,0.f,0.f,0.f}, wr1 = {0.f,0.f,0.f,0.f};
                    #pragma unroll
                    for (int v = 0; v < 4; ++v) {
                        wr0 += rdv[ep][v] * wa[v]; wr1 += rdv[ep][v] * wb[v];
                    }
                    bf16_8 a;
                    #pragma unroll
                    for (int c = 0; c < 4; ++c)
                        a[c]   = (__bf16)silu_f((float)ha[c]   + (float)hb[c]   + wr0[c]);
                    #pragma unroll
                    for (int c = 0; c < 4; ++c)
                        a[4+c] = (__bf16)silu_f((float)ha[4+c] + (float)hb[4+c] + wr1[c]);
                    af[ep][kh] = a;
                }
            }
            // m = silu(s1@We2 + be2) -> per-env transposed staging (MFMA-dense: setprio)
            __builtin_amdgcn_s_setprio(1);
            #pragma unroll
            for (int ep = 0; ep < ENVW; ++ep) {
                __bf16* mT = &mstT[wv][ep][0];
                #pragma unroll
                for (int nt = 0; nt < 4; ++nt) {
                    f32x4 acc = {0.f,0.f,0.f,0.f};
                    acc = MFMA(af[ep][0], w2f[nt][0], acc);
                    acc = MFMA(af[ep][1], w2f[nt][1], acc);
                    bf16_4 mv;
                    #pragma unroll
                    for (int r = 0; r < 4; ++r) mv[r] = (__bf16)silu_f(acc[r] + be2q[nt]);
                    *(bf16_4*)(mT + (nt*16 + n16)*LDT + q*4) = mv;
                }
            }
            __builtin_amdgcn_s_setprio(0);
            // wc = m@Wx + bx via MFMA (per env)
            #pragma unroll
            for (int ep = 0; ep < ENVW; ++ep) {
                const __bf16* mT = &mstT[wv][ep][0];
                bf16_8 aw0, aw1;
                #pragma unroll
                for (int j2 = 0; j2 < 8; ++j2) {
                    aw0[j2] = mT[(q*8 + j2)*LDT + n16];
                    aw1[j2] = mT[(32 + q*8 + j2)*LDT + n16];
                }
                f32x4 acc = {0.f,0.f,0.f,0.f};
                acc = MFMA(aw0, wxf[0], acc);
                acc = MFMA(aw1, wxf[1], acc);
                if (n16 < 4) {
                    #pragma unroll
                    for (int r = 0; r < 4; ++r) {
                        int row = t*16 + q*4 + r;
                        if (row < NEDGE) sWcB[wv][ep][row*4 + n16] = (__bf16)(acc[r] + bxv);
                    }
                }
            }
            // agg: lane = col; vectorized b64 reads
            #pragma unroll
            for (int ep = 0; ep < ENVW; ++ep) {
                const __bf16* mT = &mstT[wv][ep][0];
                bf16_4 c0 = *(const bf16_4*)(mT + lane*LDT + 0);
                #pragma unroll
                for (int el = 0; el < 4; ++el) agg[ep][(t*16 + el)/11] += (float)c0[el];
                if (t < 8) {
                    bf16_4 c1 = *(const bf16_4*)(mT + lane*LDT + 4);
                    bf16_4 c2 = *(const bf16_4*)(mT + lane*LDT + 8);
                    bf16_4 c3 = *(const bf16_4*)(mT + lane*LDT + 12);
                    #pragma unroll
                    for (int el = 0; el < 4; ++el) {
                        agg[ep][(t*16 + 4  + el)/11] += (float)c1[el];
                        agg[ep][(t*16 + 8  + el)/11] += (float)c2[el];
                        agg[ep][(t*16 + 12 + el)/11] += (float)c3[el];
                    }
                }
            }
        }
        // agg -> sHb (Hb dead after edge loop)
        #pragma unroll
        for (int ep = 0; ep < ENVW; ++ep)
            #pragma unroll
            for (int i = 0; i < NAG; ++i) sHb[wv][ep][i*LDB + lane] = (__bf16)agg[ep][i];

        // ---- xacc (pre-update x reads) ----
        float xn[ENVW][3];
        #pragma unroll
        for (int p = 0; p < 3; ++p) {
            int idx = p*64 + lane;
            int xi = idx / 12, dv = idx % 12, v = dv & 3;
            bool act = idx < 144;
            int xic = act ? xi : 0;
            #pragma unroll
            for (int ep = 0; ep < ENVW; ++ep) {
                float xiv = sx[wv][ep][xic*16 + dv];
                float acc = 0.f;
                #pragma unroll
                for (int j2 = 0; j2 < NAG; ++j2) {
                    int e2 = xic*11 + j2 - (j2 > xic ? 1 : 0);
                    e2 = (e2 < NEDGE) ? e2 : (NEDGE - 1);
                    float term = (xiv - sx[wv][ep][j2*16 + dv]) * (float)sWcB[wv][ep][e2*4 + v];
                    acc += (j2 == xic) ? 0.f : term;
                }
                xn[ep][p] = act ? (xiv + acc * (1.0f / 11.0f)) : 0.f;
            }
        }
        // ---- Wh1: t1 = silu([h,agg]@Wh1 + bh1) -> sHa (MFMA-dense: setprio) ----
        {
            bf16_8 ah0[ENVW], ah1[ENVW], ag0[ENVW], ag1[ENVW];
            #pragma unroll
            for (int ep = 0; ep < ENVW; ++ep) {
                ah0[ep] = *(const bf16_8*)(sh[wv][ep]  + rowA*LDB + q*8);
                ah1[ep] = *(const bf16_8*)(sh[wv][ep]  + rowA*LDB + 32 + q*8);
                ag0[ep] = *(const bf16_8*)(sHb[wv][ep] + rowA*LDB + q*8);
                ag1[ep] = *(const bf16_8*)(sHb[wv][ep] + rowA*LDB + 32 + q*8);
            }
            __builtin_amdgcn_s_setprio(1);
            #pragma unroll
            for (int nt = 0; nt < 4; ++nt) {
                bf16_8 b0 = frg<WS>(wsb, L+24+nt*4+0, Wh1l, 0,  nt*16+n16, lane);
                bf16_8 b1 = frg<WS>(wsb, L+24+nt*4+1, Wh1l, 32, nt*16+n16, lane);
                bf16_8 b2 = frg<WS>(wsb, L+24+nt*4+2, Wh1l, 64, nt*16+n16, lane);
                bf16_8 b3 = frg<WS>(wsb, L+24+nt*4+3, Wh1l, 96, nt*16+n16, lane);
                #pragma unroll
                for (int ep = 0; ep < ENVW; ++ep) {
                    f32x4 acc = {0.f,0.f,0.f,0.f};
                    acc = MFMA(ah0[ep], b0, acc); acc = MFMA(ah1[ep], b1, acc);
                    acc = MFMA(ag0[ep], b2, acc); acc = MFMA(ag1[ep], b3, acc);
                    #pragma unroll
                    for (int r = 0; r < 4; ++r) {
                        int row = q*4 + r;
                        if (row < NAG) sHa[wv][ep][row*LDB + nt*16+n16] = (__bf16)silu_f(acc[r] + bh1q[nt]);
                    }
                }
            }
            __builtin_amdgcn_s_setprio(0);
        }
        // ---- x writeback; Wh2: h += t1@Wh2 + bh2 ----
        #pragma unroll
        for (int p = 0; p < 3; ++p) {
            int idx = p*64 + lane;
            if (idx < 144) {
                #pragma unroll
                for (int ep = 0; ep < ENVW; ++ep)
                    sx[wv][ep][(idx/12)*16 + idx%12] = xn[ep][p];
            }
        }
        {
            bf16_8 at0[ENVW], at1[ENVW];
            #pragma unroll
            for (int ep = 0; ep < ENVW; ++ep) {
                at0[ep] = *(const bf16_8*)(sHa[wv][ep] + rowA*LDB + q*8);
                at1[ep] = *(const bf16_8*)(sHa[wv][ep] + rowA*LDB + 32 + q*8);
            }
            #pragma unroll
            for (int nt = 0; nt < 4; ++nt) {
                bf16_8 b0 = frg<WS>(wsb, L+40+nt*2+0, Wh2l, 0,  nt*16+n16, lane);
                bf16_8 b1 = frg<WS>(wsb, L+40+nt*2+1, Wh2l, 32, nt*16+n16, lane);
                #pragma unroll
                for (int ep = 0; ep < ENVW; ++ep) {
                    f32x4 acc = {0.f,0.f,0.f,0.f};
                    acc = MFMA(at0[ep], b0, acc);
                    acc = MFMA(at1[ep], b1, acc);
                    #pragma unroll
                    for (int r = 0; r < 4; ++r) hC[ep][nt][r] += acc[r] + bh2q[nt];
                }
            }
            #pragma unroll
            for (int ep = 0; ep < ENVW; ++ep)
                #pragma unroll
                for (int nt = 0; nt < 4; ++nt)
                    #pragma unroll
                    for (int r = 0; r < 4; ++r) {
                        int row = q*4 + r;
                        if (row < NAG) sh[wv][ep][row*LDB + nt*16+n16] = (__bf16)hC[ep][nt][r];
                    }
        }
    }

    // ---- epilogue: mu only ----
    if (lane < NAG * 3) {
        int i = lane / 3, d = lane - i * 3;
        #pragma unroll
        for (int ep = 0; ep < ENVW; ++ep) {
            float mu = 0.f;
            #pragma unroll
            for (int v = 0; v < 4; ++v) mu += sx[wv][ep][i*16 + d*4 + v] * w_act[v];
            out[(env0 + ep) * (NAG*3) + lane] = mu;
        }
    }
}

extern "C" void kernel_launch(void* const* d_in, const int* in_sizes, int n_in,
                              void* d_out, int out_size, void* d_ws, size_t ws_size,
                              hipStream_t stream) {
    // inputs: h0,x0,W_embed,b_embed,We1,be1,We2,be2,Wx,bx,Wh1,bh1,Wh2,bh2,w_act,log_std,row,col
    const float* h0   = (const float*)d_in[0];
    const float* x0   = (const float*)d_in[1];
    const float* Wem  = (const float*)d_in[2];
    const float* bem  = (const float*)d_in[3];
    const float* We1  = (const float*)d_in[4];
    const float* be1  = (const float*)d_in[5];
    const float* We2  = (const float*)d_in[6];
    const float* be2  = (const float*)d_in[7];
    const float* Wx   = (const float*)d_in[8];
    const float* bx   = (const float*)d_in[9];
    const float* Wh1  = (const float*)d_in[10];
    const float* bh1  = (const float*)d_in[11];
    const float* Wh2  = (const float*)d_in[12];
    const float* bh2  = (const float*)d_in[13];
    const float* wact = (const float*)d_in[14];
    const float* lstd = (const float*)d_in[15];
    float* out = (float*)d_out;

    if (ws_size >= (size_t)WS_BYTES) {
        prep_frags<<<dim3(WS_FRAGS + 9), dim3(64), 0, stream>>>(
            Wem, We1, We2, Wh1, Wh2, be1, be2, bh1, bh2, bx, (__bf16*)d_ws);
        egnn18<true><<<dim3(NTH / (ENVW * NWAVE)), dim3(64 * NWAVE), 0, stream>>>(
            h0, x0, Wem, bem, We1, be1, We2, be2, Wx, bx,
            Wh1, bh1, Wh2, bh2, wact, lstd, (const __bf16*)d_ws, out);
    } else {
        egnn18<false><<<dim3(NTH / (ENVW * NWAVE)), dim3(64 * NWAVE), 0, stream>>>(
            h0, x0, Wem, bem, We1, be1, We2, be2, Wx, bx,
            Wh1, bh1, Wh2, bh2, wact, lstd, nullptr, out);
    }
}